// Round 1
// baseline (685.843 us; speedup 1.0000x reference)
//
#include <hip/hip_runtime.h>
#include <hip/hip_bf16.h>
#include <math.h>

// Problem constants
#define BB 4
#define NN 2048
#define MM 8192           // B*N fused column dimension
#define EPSF 1e-5f

// ---------------------------------------------------------------------------
// Kernel 1: per-batch stats: cc (coords mean), cn (mean of normalized
// normals), ncn (cn normalized). st layout: 16 floats per batch.
// ---------------------------------------------------------------------------
__global__ __launch_bounds__(256) void stats_k(const float* __restrict__ in,
                                               float* __restrict__ st) {
    int b = blockIdx.x;
    int t = threadIdx.x;
    const float* base = in + (size_t)b * 22 * NN;
    float cs0 = 0.f, cs1 = 0.f, cs2 = 0.f, ns0 = 0.f, ns1 = 0.f, ns2 = 0.f;
    for (int n = t; n < NN; n += 256) {
        float cx = base[0 * NN + n], cy = base[1 * NN + n], cz = base[2 * NN + n];
        float nx = base[3 * NN + n], ny = base[4 * NN + n], nz = base[5 * NN + n];
        float inv = 1.0f / sqrtf(nx * nx + ny * ny + nz * nz);
        cs0 += cx; cs1 += cy; cs2 += cz;
        ns0 += nx * inv; ns1 += ny * inv; ns2 += nz * inv;
    }
    __shared__ float red[6][256];
    red[0][t] = cs0; red[1][t] = cs1; red[2][t] = cs2;
    red[3][t] = ns0; red[4][t] = ns1; red[5][t] = ns2;
    __syncthreads();
    for (int s = 128; s > 0; s >>= 1) {
        if (t < s) {
            #pragma unroll
            for (int i = 0; i < 6; ++i) red[i][t] += red[i][t + s];
        }
        __syncthreads();
    }
    if (t == 0) {
        float ccx = red[0][0] / (float)NN, ccy = red[1][0] / (float)NN, ccz = red[2][0] / (float)NN;
        float cnx = red[3][0] / (float)NN, cny = red[4][0] / (float)NN, cnz = red[5][0] / (float)NN;
        float inv = 1.0f / sqrtf(cnx * cnx + cny * cny + cnz * cnz);
        float* s9 = st + b * 16;
        s9[0] = ccx; s9[1] = ccy; s9[2] = ccz;
        s9[3] = cnx; s9[4] = cny; s9[5] = cnz;
        s9[6] = cnx * inv; s9[7] = cny * inv; s9[8] = cnz * inv;
    }
}

// ---------------------------------------------------------------------------
// Kernel 2: per-point PPF features (F0 rows 0..3) and projected vectors P
// (3 planes of length M).
// ---------------------------------------------------------------------------
__device__ __forceinline__ float angle3(float ux, float uy, float uz,
                                        float vx, float vy, float vz) {
    float crx = uy * vz - uz * vy;
    float cry = uz * vx - ux * vz;
    float crz = ux * vy - uy * vx;
    float s = sqrtf(crx * crx + cry * cry + crz * crz);
    float c = ux * vx + uy * vy + uz * vz;
    return atan2f(s, c);
}

__global__ __launch_bounds__(256) void point_k(const float* __restrict__ in,
                                               const float* __restrict__ st,
                                               float* __restrict__ P,
                                               float* __restrict__ F0) {
    int idx = blockIdx.x * 256 + threadIdx.x;  // 0..MM-1
    int b = idx >> 11, n = idx & (NN - 1);
    const float* base = in + (size_t)b * 22 * NN;
    const float* s9 = st + b * 16;
    float cx = base[0 * NN + n], cy = base[1 * NN + n], cz = base[2 * NN + n];
    float nx = base[3 * NN + n], ny = base[4 * NN + n], nz = base[5 * NN + n];
    float inv = 1.0f / sqrtf(nx * nx + ny * ny + nz * nz);
    nx *= inv; ny *= inv; nz *= inv;
    float ccx = s9[0], ccy = s9[1], ccz = s9[2];
    float cnx = s9[3], cny = s9[4], cnz = s9[5];
    float ex = s9[6], ey = s9[7], ez = s9[8];
    float dx = cx - ccx, dy = cy - ccy, dz = cz - ccz;
    F0[0 * MM + idx] = angle3(cnx, cny, cnz, dx, dy, dz);
    F0[1 * MM + idx] = angle3(nx, ny, nz, dx, dy, dz);
    F0[2 * MM + idx] = angle3(cnx, cny, cnz, nx, ny, nz);
    F0[3 * MM + idx] = sqrtf(dx * dx + dy * dy + dz * dz);
    float dot = dx * ex + dy * ey + dz * ez;
    P[0 * MM + idx] = dx - dot * cnx;
    P[1 * MM + idx] = dy - dot * cny;
    P[2 * MM + idx] = dz - dot * cnz;
}

// ---------------------------------------------------------------------------
// Kernel 3: per-row median (index 1023 ascending) of pairwise angles.
// One wave per 2 rows; entire row (2048 values) lives in registers
// (32 per lane). Selection = 31-bit MSB radix select via __ballot.
// Writes F0 row 4 (alpha).
// ---------------------------------------------------------------------------
__global__ __launch_bounds__(256) void alpha_k(const float* __restrict__ P,
                                               float* __restrict__ F0) {
    __shared__ float px[NN], py[NN], pz[NN];
    int b = blockIdx.x >> 8;                 // 256 blocks per batch
    int rowBase = (blockIdx.x & 255) << 3;   // 8 rows per block
    int t = threadIdx.x;
    const float* Pb = P + b * NN;            // plane stride MM
    for (int i = t; i < NN; i += 256) {
        px[i] = Pb[i];
        py[i] = Pb[MM + i];
        pz[i] = Pb[2 * MM + i];
    }
    __syncthreads();
    int wave = t >> 6, lane = t & 63;
    for (int r = 0; r < 2; ++r) {
        int i = rowBase + wave * 2 + r;
        float ax = px[i], ay = py[i], az = pz[i];
        unsigned u[32];
        #pragma unroll
        for (int s2 = 0; s2 < 32; ++s2) {
            int j = s2 * 64 + lane;
            float bx = px[j], by = py[j], bz = pz[j];
            float crx = ay * bz - az * by;
            float cry = az * bx - ax * bz;
            float crz = ax * by - ay * bx;
            float sv = sqrtf(crx * crx + cry * cry + crz * crz);
            float cv = ax * bx + ay * by + az * bz;
            float at = atan2f(sv, cv);
            if (at <= 1e-5f) at = 100.0f;
            u[s2] = __float_as_uint(at);
        }
        unsigned prefix = 0u;
        int k = (NN - 1) / 2;  // 1023
        for (int bit = 30; bit >= 0; --bit) {
            unsigned thr = 1u << bit;
            int cnt = 0;
            #pragma unroll
            for (int s2 = 0; s2 < 32; ++s2) {
                cnt += (int)__popcll(__ballot((u[s2] ^ prefix) < thr));
            }
            if (k >= cnt) { k -= cnt; prefix |= thr; }
        }
        if (lane == 0) F0[4 * MM + b * NN + i] = __uint_as_float(prefix);
    }
}

// ---------------------------------------------------------------------------
// Kernel 4: copy one-hot channels into XCAT rows 0..15.
// ---------------------------------------------------------------------------
__global__ __launch_bounds__(256) void onehot_k(const float* __restrict__ in,
                                                float* __restrict__ XC) {
    int i = blockIdx.x * 256 + threadIdx.x;   // over 16*MM/4
    int r = i >> 11;                          // 2048 float4 per row
    int col4 = i & 2047;
    int m = col4 * 4;
    int b = m >> 11, n = m & (NN - 1);
    float4 v = *(const float4*)(in + (size_t)b * 22 * NN + (size_t)(6 + r) * NN + n);
    ((float4*)(XC + (size_t)r * MM))[col4] = v;
}

// ---------------------------------------------------------------------------
// Kernel 5: fp32 tiled GEMM: Y(Co,M) = W(Co,K) @ X(K,M). 64x64 block tile,
// BK=16, 4x4 micro-tile per thread.
// ---------------------------------------------------------------------------
__global__ __launch_bounds__(256) void gemm_k(const float* __restrict__ W,
                                              const float* __restrict__ X,
                                              float* __restrict__ Y,
                                              int Co, int K) {
    __shared__ float Ws[16][64];
    __shared__ float Xs[16][64];
    int t = threadIdx.x;
    int oBase = blockIdx.y * 64;
    int mBase = blockIdx.x * 64;
    int tm = t >> 4, tn = t & 15;
    float acc[4][4] = {{0.f}};
    int wo = t >> 2;
    int wk4 = (t & 3) * 4;
    int xm = t & 63, xk = t >> 6;

    for (int k0 = 0; k0 < K; k0 += 16) {
        #pragma unroll
        for (int i = 0; i < 4; ++i) {
            int k = wk4 + i;
            float v = 0.f;
            int o = oBase + wo;
            if (k0 + k < K && o < Co) v = W[(size_t)o * K + k0 + k];
            Ws[k][wo] = v;
        }
        #pragma unroll
        for (int r = 0; r < 4; ++r) {
            int k = xk + 4 * r;
            float v = 0.f;
            if (k0 + k < K) v = X[(size_t)(k0 + k) * MM + mBase + xm];
            Xs[k][xm] = v;
        }
        __syncthreads();
        #pragma unroll
        for (int kk = 0; kk < 16; ++kk) {
            float a0 = Ws[kk][4 * tm + 0];
            float a1 = Ws[kk][4 * tm + 1];
            float a2 = Ws[kk][4 * tm + 2];
            float a3 = Ws[kk][4 * tm + 3];
            float b0 = Xs[kk][4 * tn + 0];
            float b1 = Xs[kk][4 * tn + 1];
            float b2 = Xs[kk][4 * tn + 2];
            float b3 = Xs[kk][4 * tn + 3];
            acc[0][0] += a0 * b0; acc[0][1] += a0 * b1; acc[0][2] += a0 * b2; acc[0][3] += a0 * b3;
            acc[1][0] += a1 * b0; acc[1][1] += a1 * b1; acc[1][2] += a1 * b2; acc[1][3] += a1 * b3;
            acc[2][0] += a2 * b0; acc[2][1] += a2 * b1; acc[2][2] += a2 * b2; acc[2][3] += a2 * b3;
            acc[3][0] += a3 * b0; acc[3][1] += a3 * b1; acc[3][2] += a3 * b2; acc[3][3] += a3 * b3;
        }
        __syncthreads();
    }
    #pragma unroll
    for (int i = 0; i < 4; ++i) {
        int o = oBase + 4 * tm + i;
        if (o < Co) {
            float4 v = make_float4(acc[i][0], acc[i][1], acc[i][2], acc[i][3]);
            *(float4*)(Y + (size_t)o * MM + mBase + 4 * tn) = v;
        }
    }
}

// ---------------------------------------------------------------------------
// Kernel 6: BN stats per output channel -> scale/shift pairs.
// ---------------------------------------------------------------------------
__global__ __launch_bounds__(256) void bnstat_k(const float* __restrict__ Y,
                                                const float* __restrict__ g,
                                                const float* __restrict__ bb,
                                                float* __restrict__ ab) {
    int o = blockIdx.x;
    int t = threadIdx.x;
    const float4* row = (const float4*)(Y + (size_t)o * MM);
    float s = 0.f, sq = 0.f;
    for (int i = t; i < MM / 4; i += 256) {
        float4 v = row[i];
        s += v.x + v.y + v.z + v.w;
        sq += v.x * v.x + v.y * v.y + v.z * v.z + v.w * v.w;
    }
    __shared__ float rs[256], rq[256];
    rs[t] = s; rq[t] = sq;
    __syncthreads();
    for (int st = 128; st > 0; st >>= 1) {
        if (t < st) { rs[t] += rs[t + st]; rq[t] += rq[t + st]; }
        __syncthreads();
    }
    if (t == 0) {
        float mu = rs[0] * (1.0f / (float)MM);
        float var = rq[0] * (1.0f / (float)MM) - mu * mu;
        if (var < 0.f) var = 0.f;
        float a = g[o] * (1.0f / sqrtf(var + EPSF));
        ab[2 * o] = a;
        ab[2 * o + 1] = bb[o] - mu * a;
    }
}

// ---------------------------------------------------------------------------
// Kernel 7: normalize + ReLU in place.
// ---------------------------------------------------------------------------
__global__ __launch_bounds__(256) void bnorm_k(float* __restrict__ Y,
                                               const float* __restrict__ ab) {
    int i = blockIdx.x * 256 + threadIdx.x;  // float4 index
    int o = i >> 11;                         // 2048 float4 per row
    float a = ab[2 * o], c = ab[2 * o + 1];
    float4* p = (float4*)Y;
    float4 v = p[i];
    v.x = fmaxf(v.x * a + c, 0.f);
    v.y = fmaxf(v.y * a + c, 0.f);
    v.z = fmaxf(v.z * a + c, 0.f);
    v.w = fmaxf(v.w * a + c, 0.f);
    p[i] = v;
}

// ---------------------------------------------------------------------------
// Kernel 8: per (channel, batch) max over N, broadcast into MAXB rows.
// ---------------------------------------------------------------------------
__global__ __launch_bounds__(256) void maxb_k(float* __restrict__ XC) {
    int c = blockIdx.x >> 2, b = blockIdx.x & 3;
    const float4* src = (const float4*)(XC + (size_t)(336 + c) * MM + b * NN);
    float4* dst = (float4*)(XC + (size_t)(1360 + c) * MM + b * NN);
    int t = threadIdx.x;
    float m = -INFINITY;
    for (int i = t; i < NN / 4; i += 256) {
        float4 v = src[i];
        m = fmaxf(fmaxf(m, fmaxf(v.x, v.y)), fmaxf(v.z, v.w));
    }
    __shared__ float red[256];
    red[t] = m;
    __syncthreads();
    for (int s = 128; s > 0; s >>= 1) {
        if (t < s) red[t] = fmaxf(red[t], red[t + s]);
        __syncthreads();
    }
    float mm = red[0];
    float4 vv = make_float4(mm, mm, mm, mm);
    for (int i = t; i < NN / 4; i += 256) dst[i] = vv;
}

// ---------------------------------------------------------------------------
// Kernel 9: final bias add + layout transform to (B, 50, N).
// ---------------------------------------------------------------------------
__global__ __launch_bounds__(256) void wout_k(const float* __restrict__ OT,
                                              const float* __restrict__ bias,
                                              float* __restrict__ out) {
    int i = blockIdx.x * 256 + threadIdx.x;  // over 50*MM/4
    int o = i >> 11;
    int col4 = i & 2047;
    int m = col4 * 4;
    int b = m >> 11, n = m & (NN - 1);
    float4 v = ((const float4*)(OT + (size_t)o * MM))[col4];
    float bi = bias[o];
    v.x += bi; v.y += bi; v.z += bi; v.w += bi;
    *(float4*)(out + ((size_t)b * 50 + o) * NN + n) = v;
}

// ---------------------------------------------------------------------------
extern "C" void kernel_launch(void* const* d_in, const int* in_sizes, int n_in,
                              void* d_out, int out_size, void* d_ws, size_t ws_size,
                              hipStream_t stream) {
    const float* in = (const float*)d_in[0];
    const float* pf_w[4] = {(const float*)d_in[1], (const float*)d_in[4], (const float*)d_in[7], (const float*)d_in[10]};
    const float* pf_g[4] = {(const float*)d_in[2], (const float*)d_in[5], (const float*)d_in[8], (const float*)d_in[11]};
    const float* pf_b[4] = {(const float*)d_in[3], (const float*)d_in[6], (const float*)d_in[9], (const float*)d_in[12]};
    const float* cls_w[3] = {(const float*)d_in[13], (const float*)d_in[16], (const float*)d_in[19]};
    const float* cls_g[3] = {(const float*)d_in[14], (const float*)d_in[17], (const float*)d_in[20]};
    const float* cls_b[3] = {(const float*)d_in[15], (const float*)d_in[18], (const float*)d_in[21]};
    const float* cls3_w = (const float*)d_in[22];
    const float* cls3_bias = (const float*)d_in[23];
    float* out = (float*)d_out;

    const size_t M = MM;
    float* ws = (float*)d_ws;
    float* ST = ws;                    // 64
    float* P  = ws + 64;               // 3*M
    float* F0 = P + 3 * M;             // 5*M
    float* XC = F0 + 5 * M;            // 2384*M
    float* C1 = XC + 2384 * M;         // 256*M
    float* C2 = C1 + 256 * M;          // 256*M
    float* C3 = C2 + 256 * M;          // 128*M
    float* OT = C3 + 128 * M;          // 50*M
    float* AB = OT + 50 * M;           // 2048

    stats_k<<<BB, 256, 0, stream>>>(in, ST);
    point_k<<<MM / 256, 256, 0, stream>>>(in, ST, P, F0);
    alpha_k<<<BB * NN / 8, 256, 0, stream>>>(P, F0);
    onehot_k<<<16 * MM / 4 / 256, 256, 0, stream>>>(in, XC);

    auto layer = [&](const float* W, const float* g, const float* bbias,
                     const float* X, float* Y, int Co, int K) {
        dim3 grid(MM / 64, (Co + 63) / 64);
        gemm_k<<<grid, 256, 0, stream>>>(W, X, Y, Co, K);
        bnstat_k<<<Co, 256, 0, stream>>>(Y, g, bbias, AB);
        bnorm_k<<<Co * 8, 256, 0, stream>>>(Y, AB);
    };

    layer(pf_w[0], pf_g[0], pf_b[0], F0, XC + 16 * M, 64, 5);
    layer(pf_w[1], pf_g[1], pf_b[1], XC + 16 * M, XC + 80 * M, 128, 64);
    layer(pf_w[2], pf_g[2], pf_b[2], XC + 80 * M, XC + 208 * M, 128, 128);
    layer(pf_w[3], pf_g[3], pf_b[3], XC + 208 * M, XC + 336 * M, 1024, 128);

    maxb_k<<<1024 * BB, 256, 0, stream>>>(XC);

    layer(cls_w[0], cls_g[0], cls_b[0], XC, C1, 256, 2384);
    layer(cls_w[1], cls_g[1], cls_b[1], C1, C2, 256, 256);
    layer(cls_w[2], cls_g[2], cls_b[2], C2, C3, 128, 256);

    {
        dim3 grid(MM / 64, 1);
        gemm_k<<<grid, 256, 0, stream>>>(cls3_w, C3, OT, 50, 128);
    }
    wout_k<<<50 * MM / 4 / 256, 256, 0, stream>>>(OT, cls3_bias, out);

    (void)in_sizes; (void)n_in; (void)out_size; (void)ws_size;
}

// Round 2
// 355.885 us; speedup vs baseline: 1.9271x; 1.9271x over previous
//
#include <hip/hip_runtime.h>
#include <math.h>

#define BB 4
#define NN 2048
#define MM 8192
#define EPSF 1e-5f

typedef __bf16 bf16x8 __attribute__((ext_vector_type(8)));
typedef float f32x4 __attribute__((ext_vector_type(4)));

__device__ __forceinline__ unsigned short f2bf(float x) {
    unsigned u = __builtin_bit_cast(unsigned, x);
    u = (u + 0x7FFFu + ((u >> 16) & 1u)) >> 16;
    return (unsigned short)u;
}
__device__ __forceinline__ float bf2f(unsigned short h) {
    unsigned u = ((unsigned)h) << 16;
    return __builtin_bit_cast(float, u);
}

// ---------------------------------------------------------------------------
// per-batch stats: cc, cn, ncn
// ---------------------------------------------------------------------------
__global__ __launch_bounds__(256) void stats_k(const float* __restrict__ in,
                                               float* __restrict__ st) {
    int b = blockIdx.x;
    int t = threadIdx.x;
    const float* base = in + (size_t)b * 22 * NN;
    float cs0 = 0.f, cs1 = 0.f, cs2 = 0.f, ns0 = 0.f, ns1 = 0.f, ns2 = 0.f;
    for (int n = t; n < NN; n += 256) {
        float cx = base[0 * NN + n], cy = base[1 * NN + n], cz = base[2 * NN + n];
        float nx = base[3 * NN + n], ny = base[4 * NN + n], nz = base[5 * NN + n];
        float inv = 1.0f / sqrtf(nx * nx + ny * ny + nz * nz);
        cs0 += cx; cs1 += cy; cs2 += cz;
        ns0 += nx * inv; ns1 += ny * inv; ns2 += nz * inv;
    }
    __shared__ float red[6][256];
    red[0][t] = cs0; red[1][t] = cs1; red[2][t] = cs2;
    red[3][t] = ns0; red[4][t] = ns1; red[5][t] = ns2;
    __syncthreads();
    for (int s = 128; s > 0; s >>= 1) {
        if (t < s) {
            #pragma unroll
            for (int i = 0; i < 6; ++i) red[i][t] += red[i][t + s];
        }
        __syncthreads();
    }
    if (t == 0) {
        float ccx = red[0][0] / (float)NN, ccy = red[1][0] / (float)NN, ccz = red[2][0] / (float)NN;
        float cnx = red[3][0] / (float)NN, cny = red[4][0] / (float)NN, cnz = red[5][0] / (float)NN;
        float inv = 1.0f / sqrtf(cnx * cnx + cny * cny + cnz * cnz);
        float* s9 = st + b * 16;
        s9[0] = ccx; s9[1] = ccy; s9[2] = ccz;
        s9[3] = cnx; s9[4] = cny; s9[5] = cnz;
        s9[6] = cnx * inv; s9[7] = cny * inv; s9[8] = cnz * inv;
    }
}

__device__ __forceinline__ float angle3(float ux, float uy, float uz,
                                        float vx, float vy, float vz) {
    float crx = uy * vz - uz * vy;
    float cry = uz * vx - ux * vz;
    float crz = ux * vy - uy * vx;
    float s = sqrtf(crx * crx + cry * cry + crz * crz);
    float c = ux * vx + uy * vy + uz * vz;
    return atan2f(s, c);
}

// ---------------------------------------------------------------------------
// per-point PPF (F0 rows 0..3) + projected vectors P
// ---------------------------------------------------------------------------
__global__ __launch_bounds__(256) void point_k(const float* __restrict__ in,
                                               const float* __restrict__ st,
                                               float* __restrict__ P,
                                               float* __restrict__ F0) {
    int idx = blockIdx.x * 256 + threadIdx.x;
    int b = idx >> 11, n = idx & (NN - 1);
    const float* base = in + (size_t)b * 22 * NN;
    const float* s9 = st + b * 16;
    float cx = base[0 * NN + n], cy = base[1 * NN + n], cz = base[2 * NN + n];
    float nx = base[3 * NN + n], ny = base[4 * NN + n], nz = base[5 * NN + n];
    float inv = 1.0f / sqrtf(nx * nx + ny * ny + nz * nz);
    nx *= inv; ny *= inv; nz *= inv;
    float ccx = s9[0], ccy = s9[1], ccz = s9[2];
    float cnx = s9[3], cny = s9[4], cnz = s9[5];
    float ex = s9[6], ey = s9[7], ez = s9[8];
    float dx = cx - ccx, dy = cy - ccy, dz = cz - ccz;
    F0[0 * MM + idx] = angle3(cnx, cny, cnz, dx, dy, dz);
    F0[1 * MM + idx] = angle3(nx, ny, nz, dx, dy, dz);
    F0[2 * MM + idx] = angle3(cnx, cny, cnz, nx, ny, nz);
    F0[3 * MM + idx] = sqrtf(dx * dx + dy * dy + dz * dz);
    float dot = dx * ex + dy * ey + dz * ez;
    P[0 * MM + idx] = dx - dot * cnx;
    P[1 * MM + idx] = dy - dot * cny;
    P[2 * MM + idx] = dz - dot * cnz;
}

// ---------------------------------------------------------------------------
// per-row median of pairwise angles (register-resident radix select)
// ---------------------------------------------------------------------------
__global__ __launch_bounds__(256) void alpha_k(const float* __restrict__ P,
                                               float* __restrict__ F0) {
    __shared__ float px[NN], py[NN], pz[NN];
    int b = blockIdx.x >> 8;
    int rowBase = (blockIdx.x & 255) << 3;
    int t = threadIdx.x;
    const float* Pb = P + b * NN;
    for (int i = t; i < NN; i += 256) {
        px[i] = Pb[i];
        py[i] = Pb[MM + i];
        pz[i] = Pb[2 * MM + i];
    }
    __syncthreads();
    int wave = t >> 6, lane = t & 63;
    for (int r = 0; r < 2; ++r) {
        int i = rowBase + wave * 2 + r;
        float ax = px[i], ay = py[i], az = pz[i];
        unsigned u[32];
        #pragma unroll
        for (int s2 = 0; s2 < 32; ++s2) {
            int j = s2 * 64 + lane;
            float bx = px[j], by = py[j], bz = pz[j];
            float crx = ay * bz - az * by;
            float cry = az * bx - ax * bz;
            float crz = ax * by - ay * bx;
            float sv = sqrtf(crx * crx + cry * cry + crz * crz);
            float cv = ax * bx + ay * by + az * bz;
            float at = atan2f(sv, cv);
            if (at <= 1e-5f) at = 100.0f;
            u[s2] = __float_as_uint(at);
        }
        unsigned prefix = 0u;
        int k = (NN - 1) / 2;
        for (int bit = 30; bit >= 0; --bit) {
            unsigned thr = 1u << bit;
            int cnt = 0;
            #pragma unroll
            for (int s2 = 0; s2 < 32; ++s2) {
                cnt += (int)__popcll(__ballot((u[s2] ^ prefix) < thr));
            }
            if (k >= cnt) { k -= cnt; prefix |= thr; }
        }
        if (lane == 0) F0[4 * MM + b * NN + i] = __uint_as_float(prefix);
    }
}

// ---------------------------------------------------------------------------
// zero a small region (SUMS + MAXB)
// ---------------------------------------------------------------------------
__global__ void zero_k(float* __restrict__ p) {
    p[blockIdx.x * 256 + threadIdx.x] = 0.f;
}

// ---------------------------------------------------------------------------
// convert all weights to bf16 (with K-pad for cls0, O-pad for cls3)
// ---------------------------------------------------------------------------
__global__ __launch_bounds__(256) void wconv_k(const float* __restrict__ w1, const float* __restrict__ w2,
                                               const float* __restrict__ w3, const float* __restrict__ w4,
                                               const float* __restrict__ w5, const float* __restrict__ w6,
                                               const float* __restrict__ w7, unsigned short* __restrict__ Wb) {
    int idx = blockIdx.x * 256 + threadIdx.x;
    unsigned short v;
    if (idx < 8192) v = f2bf(w1[idx]);
    else if (idx < 24576) v = f2bf(w2[idx - 8192]);
    else if (idx < 155648) v = f2bf(w3[idx - 24576]);
    else if (idx < 770048) {
        int l = idx - 155648;
        int o = l / 2400, k = l - o * 2400;
        v = (k < 2384) ? f2bf(w4[o * 2384 + k]) : (unsigned short)0;
    } else if (idx < 835584) v = f2bf(w5[idx - 770048]);
    else if (idx < 868352) v = f2bf(w6[idx - 835584]);
    else {
        int l = idx - 868352;
        int o = l >> 7, k = l & 127;
        v = (o < 50) ? f2bf(w7[o * 128 + k]) : (unsigned short)0;
    }
    Wb[idx] = v;
}

// ---------------------------------------------------------------------------
// one-hot rows 0..15 of XCb + zero pad cols 2384..2399
// ---------------------------------------------------------------------------
__global__ __launch_bounds__(256) void onehot_k(const float* __restrict__ in,
                                                unsigned short* __restrict__ XCb) {
    int m = blockIdx.x * 256 + threadIdx.x;
    int b = m >> 11, n = m & (NN - 1);
    const float* src = in + (size_t)b * 22 * NN + 6 * NN + n;
    unsigned short vals[16];
    #pragma unroll
    for (int r = 0; r < 16; ++r) vals[r] = f2bf(src[(size_t)r * NN]);
    ushort4* dst = (ushort4*)&XCb[(size_t)m * 2400];
    #pragma unroll
    for (int q = 0; q < 4; ++q)
        dst[q] = make_ushort4(vals[4 * q], vals[4 * q + 1], vals[4 * q + 2], vals[4 * q + 3]);
    ushort4 z = make_ushort4(0, 0, 0, 0);
    ushort4* pz = (ushort4*)&XCb[(size_t)m * 2400 + 2384];
    pz[0] = z; pz[1] = z; pz[2] = z; pz[3] = z;
}

// ---------------------------------------------------------------------------
// pf0: tiny K=5 GEMM, Y (M,64) fp32
// ---------------------------------------------------------------------------
__global__ __launch_bounds__(256) void pf0_k(const float* __restrict__ F0,
                                             const float* __restrict__ W,
                                             float* __restrict__ Y) {
    __shared__ float ws[320];
    int t = threadIdx.x;
    for (int i = t; i < 320; i += 256) ws[i] = W[i];
    __syncthreads();
    int m = blockIdx.x * 256 + t;
    float x0 = F0[m], x1 = F0[MM + m], x2 = F0[2 * MM + m], x3 = F0[3 * MM + m], x4 = F0[4 * MM + m];
    float* ym = Y + (size_t)m * 64;
    #pragma unroll
    for (int o = 0; o < 64; ++o) {
        const float* wo = &ws[o * 5];
        ym[o] = wo[0] * x0 + wo[1] * x1 + wo[2] * x2 + wo[3] * x3 + wo[4] * x4;
    }
}

// ---------------------------------------------------------------------------
// bf16 MFMA GEMM: Y(M,Co) += ... actually Y = X(M,K)bf16 * W(Co,K)bf16^T
// 64x64 tile, 4 waves, each wave 32x32 via 2x2 16x16x32 MFMA frags.
// ---------------------------------------------------------------------------
__global__ __launch_bounds__(256) void mgemm_k(const unsigned short* __restrict__ X, int ldx,
                                               const unsigned short* __restrict__ W, int ldw,
                                               float* __restrict__ Y, int Co, int K) {
    __shared__ unsigned short As[64 * 32];
    __shared__ unsigned short Bs[64 * 32];
    int t = threadIdx.x;
    int mBase = blockIdx.x * 64;
    int oBase = blockIdx.y * 64;
    int lane = t & 63, w = t >> 6;
    int warpM = (w & 1) * 32, warpO = (w >> 1) * 32;
    f32x4 acc[2][2];
    #pragma unroll
    for (int i = 0; i < 2; ++i)
        #pragma unroll
        for (int j = 0; j < 2; ++j) acc[i][j] = (f32x4){0.f, 0.f, 0.f, 0.f};
    int lr = t >> 2;
    int lc = (t & 3) * 8;
    const unsigned short* Xp = X + (size_t)(mBase + lr) * ldx + lc;
    const unsigned short* Wp = W + (size_t)(oBase + lr) * ldw + lc;
    int ar0 = (warpM + (lane & 15)) * 32 + (lane >> 4) * 8;
    int br0 = (warpO + (lane & 15)) * 32 + (lane >> 4) * 8;
    for (int k0 = 0; k0 < K; k0 += 32) {
        uint4 xa = *(const uint4*)(Xp + k0);
        uint4 wb = *(const uint4*)(Wp + k0);
        __syncthreads();
        *(uint4*)&As[lr * 32 + lc] = xa;
        *(uint4*)&Bs[lr * 32 + lc] = wb;
        __syncthreads();
        bf16x8 a0 = __builtin_bit_cast(bf16x8, *(const uint4*)&As[ar0]);
        bf16x8 a1 = __builtin_bit_cast(bf16x8, *(const uint4*)&As[ar0 + 16 * 32]);
        bf16x8 b0 = __builtin_bit_cast(bf16x8, *(const uint4*)&Bs[br0]);
        bf16x8 b1 = __builtin_bit_cast(bf16x8, *(const uint4*)&Bs[br0 + 16 * 32]);
        acc[0][0] = __builtin_amdgcn_mfma_f32_16x16x32_bf16(a0, b0, acc[0][0], 0, 0, 0);
        acc[0][1] = __builtin_amdgcn_mfma_f32_16x16x32_bf16(a0, b1, acc[0][1], 0, 0, 0);
        acc[1][0] = __builtin_amdgcn_mfma_f32_16x16x32_bf16(a1, b0, acc[1][0], 0, 0, 0);
        acc[1][1] = __builtin_amdgcn_mfma_f32_16x16x32_bf16(a1, b1, acc[1][1], 0, 0, 0);
    }
    #pragma unroll
    for (int i = 0; i < 2; ++i) {
        #pragma unroll
        for (int j = 0; j < 2; ++j) {
            int m0 = mBase + warpM + i * 16 + (lane >> 4) * 4;
            int o = oBase + warpO + j * 16 + (lane & 15);
            #pragma unroll
            for (int r = 0; r < 4; ++r)
                Y[(size_t)(m0 + r) * Co + o] = acc[i][j][r];
        }
    }
}

// ---------------------------------------------------------------------------
// BN stats: patch-reduce (512 rows x 64 cols per block) + global atomics
// ---------------------------------------------------------------------------
__global__ __launch_bounds__(256) void bnstat_k(const float* __restrict__ Y, int Co,
                                                float* __restrict__ sums) {
    int o0 = blockIdx.x * 64;
    int m0 = blockIdx.y * 512;
    int t = threadIdx.x, ol = t & 63, mg = t >> 6;
    float s = 0.f, q = 0.f;
    const float* p = Y + (size_t)(m0 + mg) * Co + o0 + ol;
    for (int i = 0; i < 128; ++i) {
        float v = p[(size_t)i * 4 * Co];
        s += v; q += v * v;
    }
    __shared__ float ls[4][64], lq[4][64];
    ls[mg][ol] = s; lq[mg][ol] = q;
    __syncthreads();
    if (mg == 0) {
        s = ls[0][ol] + ls[1][ol] + ls[2][ol] + ls[3][ol];
        q = lq[0][ol] + lq[1][ol] + lq[2][ol] + lq[3][ol];
        atomicAdd(&sums[o0 + ol], s);
        atomicAdd(&sums[1024 + o0 + ol], q);
    }
}

__global__ void bnfin_k(const float* __restrict__ sums, const float* __restrict__ g,
                        const float* __restrict__ bb, float* __restrict__ ab, int Co) {
    int o = blockIdx.x * 256 + threadIdx.x;
    if (o >= Co) return;
    float mu = sums[o] * (1.f / 8192.f);
    float var = sums[1024 + o] * (1.f / 8192.f) - mu * mu;
    var = fmaxf(var, 0.f);
    float a = g[o] / sqrtf(var + EPSF);
    ab[2 * o] = a;
    ab[2 * o + 1] = bb[o] - mu * a;
}

// ---------------------------------------------------------------------------
// BN normalize + ReLU + bf16 store into dest slice (ldd-strided)
// ---------------------------------------------------------------------------
__global__ __launch_bounds__(256) void bnorm_k(const float* __restrict__ Y, const float* __restrict__ ab,
                                               unsigned short* __restrict__ dst, int ldd, int shift) {
    int idx4 = blockIdx.x * 256 + threadIdx.x;
    int m = idx4 >> shift;
    int o4 = idx4 & ((1 << shift) - 1);
    float4 v = ((const float4*)Y)[idx4];
    float4 p0 = *(const float4*)&ab[8 * o4];
    float4 p1 = *(const float4*)&ab[8 * o4 + 4];
    ushort4 u;
    u.x = f2bf(fmaxf(v.x * p0.x + p0.y, 0.f));
    u.y = f2bf(fmaxf(v.y * p0.z + p0.w, 0.f));
    u.z = f2bf(fmaxf(v.z * p1.x + p1.y, 0.f));
    u.w = f2bf(fmaxf(v.w * p1.z + p1.w, 0.f));
    *(ushort4*)&dst[(size_t)m * ldd + o4 * 4] = u;
}

// ---------------------------------------------------------------------------
// max over N per (b, channel) from pf3's bf16 slice
// ---------------------------------------------------------------------------
__global__ __launch_bounds__(256) void maxred_k(const unsigned short* __restrict__ Xs,
                                                float* __restrict__ maxbuf) {
    int o0 = blockIdx.x * 64;
    int b = blockIdx.y;
    int rc = blockIdx.z;
    int t = threadIdx.x, ol = t & 63, mg = t >> 6;
    float mx = 0.f;
    for (int i = 0; i < 128; ++i) {
        int m = b * NN + rc * 512 + i * 4 + mg;
        mx = fmaxf(mx, bf2f(Xs[(size_t)m * 2400 + o0 + ol]));
    }
    __shared__ float ls[4][64];
    ls[mg][ol] = mx;
    __syncthreads();
    if (mg == 0) {
        mx = fmaxf(fmaxf(ls[0][ol], ls[1][ol]), fmaxf(ls[2][ol], ls[3][ol]));
        atomicMax((unsigned*)&maxbuf[b * 1024 + o0 + ol], __builtin_bit_cast(unsigned, mx));
    }
}

__global__ __launch_bounds__(256) void maxbc_k(const float* __restrict__ maxbuf,
                                               unsigned short* __restrict__ XCb) {
    int idx8 = blockIdx.x * 256 + threadIdx.x;
    int m = idx8 >> 7;
    int o8 = (idx8 & 127) * 8;
    int b = m >> 11;
    const float* mb = maxbuf + b * 1024 + o8;
    ushort4 u0 = make_ushort4(f2bf(mb[0]), f2bf(mb[1]), f2bf(mb[2]), f2bf(mb[3]));
    ushort4 u1 = make_ushort4(f2bf(mb[4]), f2bf(mb[5]), f2bf(mb[6]), f2bf(mb[7]));
    *(ushort4*)&XCb[(size_t)m * 2400 + 1360 + o8] = u0;
    *(ushort4*)&XCb[(size_t)m * 2400 + 1360 + o8 + 4] = u1;
}

// ---------------------------------------------------------------------------
// final: OT(M,128) fp32 -> out (B,50,N) + bias, via LDS transpose
// ---------------------------------------------------------------------------
__global__ __launch_bounds__(256) void wout_k(const float* __restrict__ OT,
                                              const float* __restrict__ bias,
                                              float* __restrict__ out) {
    __shared__ float ts[128][65];
    int t = threadIdx.x;
    int m0 = blockIdx.x * 128;
    #pragma unroll
    for (int i = 0; i < 8; ++i) {
        int idx4 = t + 256 * i;
        int row = idx4 >> 4, c4 = (idx4 & 15) * 4;
        float4 v = *(const float4*)&OT[(size_t)(m0 + row) * 128 + c4];
        ts[row][c4] = v.x; ts[row][c4 + 1] = v.y; ts[row][c4 + 2] = v.z; ts[row][c4 + 3] = v.w;
    }
    __syncthreads();
    int b = m0 >> 11, n0 = m0 & (NN - 1);
    #pragma unroll
    for (int j = 0; j < 25; ++j) {
        int idx = t + 256 * j;
        int o = idx >> 7, nl = idx & 127;
        out[((size_t)b * 50 + o) * NN + n0 + nl] = ts[nl][o] + bias[o];
    }
}

// ---------------------------------------------------------------------------
extern "C" void kernel_launch(void* const* d_in, const int* in_sizes, int n_in,
                              void* d_out, int out_size, void* d_ws, size_t ws_size,
                              hipStream_t stream) {
    const float* in = (const float*)d_in[0];
    const float* pf0_w = (const float*)d_in[1];
    const float* pf_g[4] = {(const float*)d_in[2], (const float*)d_in[5], (const float*)d_in[8], (const float*)d_in[11]};
    const float* pf_b[4] = {(const float*)d_in[3], (const float*)d_in[6], (const float*)d_in[9], (const float*)d_in[12]};
    const float* pf_w[4] = {(const float*)d_in[1], (const float*)d_in[4], (const float*)d_in[7], (const float*)d_in[10]};
    const float* cls_w[3] = {(const float*)d_in[13], (const float*)d_in[16], (const float*)d_in[19]};
    const float* cls_g[3] = {(const float*)d_in[14], (const float*)d_in[17], (const float*)d_in[20]};
    const float* cls_b[3] = {(const float*)d_in[15], (const float*)d_in[18], (const float*)d_in[21]};
    const float* cls3_w = (const float*)d_in[22];
    const float* cls3_bias = (const float*)d_in[23];
    float* out = (float*)d_out;

    char* wsb = (char*)d_ws;
    float* ST = (float*)(wsb + 0);
    float* P = (float*)(wsb + 256);
    float* F0 = (float*)(wsb + 98560);
    float* SUMS = (float*)(wsb + 262400);
    float* MAXB = (float*)(wsb + 270592);
    float* AB = (float*)(wsb + 286976);
    unsigned short* WB = (unsigned short*)(wsb + 295168);
    unsigned short* XCb = (unsigned short*)(wsb + 2064640);
    unsigned short* C1b = (unsigned short*)(wsb + 41386240);
    unsigned short* C2b = (unsigned short*)(wsb + 45580544);
    unsigned short* C3b = (unsigned short*)(wsb + 49774848);
    float* Y = (float*)(wsb + 51872000);

    zero_k<<<24, 256, 0, stream>>>(SUMS);  // SUMS (2048) + MAXB (4096)
    wconv_k<<<3456, 256, 0, stream>>>(pf_w[1], pf_w[2], pf_w[3], cls_w[0], cls_w[1], cls_w[2], cls3_w, WB);
    stats_k<<<BB, 256, 0, stream>>>(in, ST);
    point_k<<<MM / 256, 256, 0, stream>>>(in, ST, P, F0);
    alpha_k<<<BB * NN / 8, 256, 0, stream>>>(P, F0);
    onehot_k<<<MM / 256, 256, 0, stream>>>(in, XCb);

    auto bn = [&](int Co, const float* g, const float* bbias, unsigned short* dst, int ldd, int shift) {
        bnstat_k<<<dim3(Co / 64, 16), 256, 0, stream>>>(Y, Co, SUMS);
        bnfin_k<<<(Co + 255) / 256, 256, 0, stream>>>(SUMS, g, bbias, AB, Co);
        bnorm_k<<<8 * Co, 256, 0, stream>>>(Y, AB, dst, ldd, shift);
        zero_k<<<24, 256, 0, stream>>>(SUMS);  // re-zero SUMS (+MAXB harmless before maxred)
    };

    // pf0
    pf0_k<<<MM / 256, 256, 0, stream>>>(F0, pf0_w, Y);
    bn(64, pf_g[0], pf_b[0], XCb + 16, 2400, 4);
    // pf1
    mgemm_k<<<dim3(128, 2), 256, 0, stream>>>(XCb + 16, 2400, WB, 64, Y, 128, 64);
    bn(128, pf_g[1], pf_b[1], XCb + 80, 2400, 5);
    // pf2
    mgemm_k<<<dim3(128, 2), 256, 0, stream>>>(XCb + 80, 2400, WB + 8192, 128, Y, 128, 128);
    bn(128, pf_g[2], pf_b[2], XCb + 208, 2400, 5);
    // pf3
    mgemm_k<<<dim3(128, 16), 256, 0, stream>>>(XCb + 208, 2400, WB + 24576, 128, Y, 1024, 128);
    bn(1024, pf_g[3], pf_b[3], XCb + 336, 2400, 8);
    // max feature
    maxred_k<<<dim3(16, 4, 4), 256, 0, stream>>>(XCb + 336, MAXB);
    maxbc_k<<<4096, 256, 0, stream>>>(MAXB, XCb);
    // cls0
    mgemm_k<<<dim3(128, 4), 256, 0, stream>>>(XCb, 2400, WB + 155648, 2400, Y, 256, 2400);
    bn(256, cls_g[0], cls_b[0], C1b, 256, 6);
    // cls1
    mgemm_k<<<dim3(128, 4), 256, 0, stream>>>(C1b, 256, WB + 770048, 256, Y, 256, 256);
    bn(256, cls_g[1], cls_b[1], C2b, 256, 6);
    // cls2
    mgemm_k<<<dim3(128, 2), 256, 0, stream>>>(C2b, 256, WB + 835584, 256, Y, 128, 256);
    bn(128, cls_g[2], cls_b[2], C3b, 128, 5);
    // cls3 (padded to 128 outputs, rows 50..127 are zero weights)
    mgemm_k<<<dim3(128, 2), 256, 0, stream>>>(C3b, 128, WB + 868352, 128, Y, 128, 128);
    wout_k<<<MM / 128, 256, 0, stream>>>(Y, cls3_bias, out);

    (void)in_sizes; (void)n_in; (void)out_size; (void)ws_size;
}

// Round 4
// 286.611 us; speedup vs baseline: 2.3929x; 1.2417x over previous
//
#include <hip/hip_runtime.h>
#include <math.h>

#define BB 4
#define NN 2048
#define MM 8192
#define EPSF 1e-5f

typedef _Float16 half8 __attribute__((ext_vector_type(8)));
typedef float f32x4 __attribute__((ext_vector_type(4)));

// fp16 storage (RTNE via v_cvt_f16_f32)
__device__ __forceinline__ unsigned short f2h(float x) {
    _Float16 h = (_Float16)x;
    return __builtin_bit_cast(unsigned short, h);
}
__device__ __forceinline__ float h2f(unsigned short u) {
    return (float)__builtin_bit_cast(_Float16, u);
}

// ---------------------------------------------------------------------------
// per-batch stats: cc, cn, ncn
// ---------------------------------------------------------------------------
__global__ __launch_bounds__(256) void stats_k(const float* __restrict__ in,
                                               float* __restrict__ st) {
    int b = blockIdx.x;
    int t = threadIdx.x;
    const float* base = in + (size_t)b * 22 * NN;
    float cs0 = 0.f, cs1 = 0.f, cs2 = 0.f, ns0 = 0.f, ns1 = 0.f, ns2 = 0.f;
    for (int n = t; n < NN; n += 256) {
        float cx = base[0 * NN + n], cy = base[1 * NN + n], cz = base[2 * NN + n];
        float nx = base[3 * NN + n], ny = base[4 * NN + n], nz = base[5 * NN + n];
        float inv = 1.0f / sqrtf(nx * nx + ny * ny + nz * nz);
        cs0 += cx; cs1 += cy; cs2 += cz;
        ns0 += nx * inv; ns1 += ny * inv; ns2 += nz * inv;
    }
    __shared__ float red[6][256];
    red[0][t] = cs0; red[1][t] = cs1; red[2][t] = cs2;
    red[3][t] = ns0; red[4][t] = ns1; red[5][t] = ns2;
    __syncthreads();
    for (int s = 128; s > 0; s >>= 1) {
        if (t < s) {
            #pragma unroll
            for (int i = 0; i < 6; ++i) red[i][t] += red[i][t + s];
        }
        __syncthreads();
    }
    if (t == 0) {
        float ccx = red[0][0] / (float)NN, ccy = red[1][0] / (float)NN, ccz = red[2][0] / (float)NN;
        float cnx = red[3][0] / (float)NN, cny = red[4][0] / (float)NN, cnz = red[5][0] / (float)NN;
        float inv = 1.0f / sqrtf(cnx * cnx + cny * cny + cnz * cnz);
        float* s9 = st + b * 16;
        s9[0] = ccx; s9[1] = ccy; s9[2] = ccz;
        s9[3] = cnx; s9[4] = cny; s9[5] = cnz;
        s9[6] = cnx * inv; s9[7] = cny * inv; s9[8] = cnz * inv;
    }
}

__device__ __forceinline__ float angle3(float ux, float uy, float uz,
                                        float vx, float vy, float vz) {
    float crx = uy * vz - uz * vy;
    float cry = uz * vx - ux * vz;
    float crz = ux * vy - uy * vx;
    float s = sqrtf(crx * crx + cry * cry + crz * crz);
    float c = ux * vx + uy * vy + uz * vz;
    return atan2f(s, c);
}

// ---------------------------------------------------------------------------
// per-point PPF (F0 rows 0..3) + projected vectors P
// ---------------------------------------------------------------------------
__global__ __launch_bounds__(256) void point_k(const float* __restrict__ in,
                                               const float* __restrict__ st,
                                               float* __restrict__ P,
                                               float* __restrict__ F0) {
    int idx = blockIdx.x * 256 + threadIdx.x;
    int b = idx >> 11, n = idx & (NN - 1);
    const float* base = in + (size_t)b * 22 * NN;
    const float* s9 = st + b * 16;
    float cx = base[0 * NN + n], cy = base[1 * NN + n], cz = base[2 * NN + n];
    float nx = base[3 * NN + n], ny = base[4 * NN + n], nz = base[5 * NN + n];
    float inv = 1.0f / sqrtf(nx * nx + ny * ny + nz * nz);
    nx *= inv; ny *= inv; nz *= inv;
    float ccx = s9[0], ccy = s9[1], ccz = s9[2];
    float cnx = s9[3], cny = s9[4], cnz = s9[5];
    float ex = s9[6], ey = s9[7], ez = s9[8];
    float dx = cx - ccx, dy = cy - ccy, dz = cz - ccz;
    F0[0 * MM + idx] = angle3(cnx, cny, cnz, dx, dy, dz);
    F0[1 * MM + idx] = angle3(nx, ny, nz, dx, dy, dz);
    F0[2 * MM + idx] = angle3(cnx, cny, cnz, nx, ny, nz);
    F0[3 * MM + idx] = sqrtf(dx * dx + dy * dy + dz * dz);
    float dot = dx * ex + dy * ey + dz * ez;
    P[0 * MM + idx] = dx - dot * cnx;
    P[1 * MM + idx] = dy - dot * cny;
    P[2 * MM + idx] = dz - dot * cnz;
}

// ---------------------------------------------------------------------------
// per-row median of pairwise angles. Monotone key = tan^2(theta/2) =
// ss/(c+|a||b|)^2 (no atan2/sqrt in pair loop). at<=1e-5 <=> key<=2.5e-11 ->
// +INF (sorts last like reference's 100). 24-bit radix select via __ballot;
// value reconstructed once per row as 2*atan(sqrt(key)).
// ---------------------------------------------------------------------------
__global__ __launch_bounds__(256) void alpha_k(const float* __restrict__ P,
                                               float* __restrict__ F0) {
    __shared__ float4 pq[NN];
    int b = blockIdx.x >> 8;
    int rowBase = (blockIdx.x & 255) << 3;
    int t = threadIdx.x;
    const float* Pb = P + b * NN;
    for (int i = t; i < NN; i += 256) {
        float x = Pb[i], y = Pb[MM + i], z = Pb[2 * MM + i];
        pq[i] = make_float4(x, y, z, sqrtf(x * x + y * y + z * z));
    }
    __syncthreads();
    int wave = t >> 6, lane = t & 63;
    int i0 = rowBase + wave * 2;
    float4 a0 = pq[i0];
    float4 a1 = pq[i0 + 1];
    unsigned u0[32], u1[32];
    #pragma unroll
    for (int s2 = 0; s2 < 32; ++s2) {
        int j = s2 * 64 + lane;
        float4 bv = pq[j];
        {
            float crx = a0.y * bv.z - a0.z * bv.y;
            float cry = a0.z * bv.x - a0.x * bv.z;
            float crz = a0.x * bv.y - a0.y * bv.x;
            float ss = crx * crx + cry * cry + crz * crz;
            float c = a0.x * bv.x + a0.y * bv.y + a0.z * bv.z;
            float den = c + a0.w * bv.w;
            float rc = __builtin_amdgcn_rcpf(den);
            float key = ss * rc * rc;
            if (key <= 2.5e-11f) key = __builtin_inff();
            u0[s2] = __float_as_uint(key);
        }
        {
            float crx = a1.y * bv.z - a1.z * bv.y;
            float cry = a1.z * bv.x - a1.x * bv.z;
            float crz = a1.x * bv.y - a1.y * bv.x;
            float ss = crx * crx + cry * cry + crz * crz;
            float c = a1.x * bv.x + a1.y * bv.y + a1.z * bv.z;
            float den = c + a1.w * bv.w;
            float rc = __builtin_amdgcn_rcpf(den);
            float key = ss * rc * rc;
            if (key <= 2.5e-11f) key = __builtin_inff();
            u1[s2] = __float_as_uint(key);
        }
    }
    unsigned p0 = 0u, p1 = 0u;
    int k0 = 1023, k1 = 1023;
    for (int bit = 30; bit >= 7; --bit) {
        unsigned thr = 1u << bit;
        int c0 = 0, c1 = 0;
        #pragma unroll
        for (int s2 = 0; s2 < 32; ++s2) {
            c0 += (int)__popcll(__ballot((u0[s2] ^ p0) < thr));
            c1 += (int)__popcll(__ballot((u1[s2] ^ p1) < thr));
        }
        if (k0 >= c0) { k0 -= c0; p0 |= thr; }
        if (k1 >= c1) { k1 -= c1; p1 |= thr; }
    }
    if (lane == 0) {
        F0[4 * MM + b * NN + i0] = 2.0f * atanf(sqrtf(__uint_as_float(p0)));
        F0[4 * MM + b * NN + i0 + 1] = 2.0f * atanf(sqrtf(__uint_as_float(p1)));
    }
}

// ---------------------------------------------------------------------------
// zero a small region (SUMS + MAXB)
// ---------------------------------------------------------------------------
__global__ void zero_k(float* __restrict__ p) {
    p[blockIdx.x * 256 + threadIdx.x] = 0.f;
}

// ---------------------------------------------------------------------------
// convert all weights to fp16 (K-pad for cls0, O-pad for cls3)
// ---------------------------------------------------------------------------
__global__ __launch_bounds__(256) void wconv_k(const float* __restrict__ w1, const float* __restrict__ w2,
                                               const float* __restrict__ w3, const float* __restrict__ w4,
                                               const float* __restrict__ w5, const float* __restrict__ w6,
                                               const float* __restrict__ w7, unsigned short* __restrict__ Wb) {
    int idx = blockIdx.x * 256 + threadIdx.x;
    unsigned short v;
    if (idx < 8192) v = f2h(w1[idx]);
    else if (idx < 24576) v = f2h(w2[idx - 8192]);
    else if (idx < 155648) v = f2h(w3[idx - 24576]);
    else if (idx < 770048) {
        int l = idx - 155648;
        int o = l / 2400, k = l - o * 2400;
        v = (k < 2384) ? f2h(w4[o * 2384 + k]) : (unsigned short)0;
    } else if (idx < 835584) v = f2h(w5[idx - 770048]);
    else if (idx < 868352) v = f2h(w6[idx - 835584]);
    else {
        int l = idx - 868352;
        int o = l >> 7, k = l & 127;
        v = (o < 50) ? f2h(w7[o * 128 + k]) : (unsigned short)0;
    }
    Wb[idx] = v;
}

// ---------------------------------------------------------------------------
// one-hot rows 0..15 of XCb + zero pad cols 2384..2399
// ---------------------------------------------------------------------------
__global__ __launch_bounds__(256) void onehot_k(const float* __restrict__ in,
                                                unsigned short* __restrict__ XCb) {
    int m = blockIdx.x * 256 + threadIdx.x;
    int b = m >> 11, n = m & (NN - 1);
    const float* src = in + (size_t)b * 22 * NN + 6 * NN + n;
    unsigned short vals[16];
    #pragma unroll
    for (int r = 0; r < 16; ++r) vals[r] = f2h(src[(size_t)r * NN]);
    ushort4* dst = (ushort4*)&XCb[(size_t)m * 2400];
    #pragma unroll
    for (int q = 0; q < 4; ++q)
        dst[q] = make_ushort4(vals[4 * q], vals[4 * q + 1], vals[4 * q + 2], vals[4 * q + 3]);
    ushort4 z = make_ushort4(0, 0, 0, 0);
    ushort4* pz = (ushort4*)&XCb[(size_t)m * 2400 + 2384];
    pz[0] = z; pz[1] = z; pz[2] = z; pz[3] = z;
}

// ---------------------------------------------------------------------------
// pf0: tiny K=5 GEMM, Y (M,64) fp32
// ---------------------------------------------------------------------------
__global__ __launch_bounds__(256) void pf0_k(const float* __restrict__ F0,
                                             const float* __restrict__ W,
                                             float* __restrict__ Y) {
    __shared__ float ws[320];
    int t = threadIdx.x;
    for (int i = t; i < 320; i += 256) ws[i] = W[i];
    __syncthreads();
    int m = blockIdx.x * 256 + t;
    float x0 = F0[m], x1 = F0[MM + m], x2 = F0[2 * MM + m], x3 = F0[3 * MM + m], x4 = F0[4 * MM + m];
    float* ym = Y + (size_t)m * 64;
    #pragma unroll
    for (int o = 0; o < 64; ++o) {
        const float* wo = &ws[o * 5];
        ym[o] = wo[0] * x0 + wo[1] * x1 + wo[2] * x2 + wo[3] * x3 + wo[4] * x4;
    }
}

// ---------------------------------------------------------------------------
// fp16 MFMA GEMM: Y(M,Co) = X(M,K) * W(Co,K)^T, 64x64 tile, 4 waves.
// Optional fused BN-stat epilogue (per-channel sum/sumsq via LDS + atomics).
// ---------------------------------------------------------------------------
__global__ __launch_bounds__(256) void mgemm_k(const unsigned short* __restrict__ X, int ldx,
                                               const unsigned short* __restrict__ W, int ldw,
                                               float* __restrict__ Y, int Co, int K,
                                               float* __restrict__ sums, int doStats) {
    __shared__ unsigned short As[64 * 32];
    __shared__ unsigned short Bs[64 * 32];
    int t = threadIdx.x;
    int mBase = blockIdx.x * 64;
    int oBase = blockIdx.y * 64;
    int lane = t & 63, w = t >> 6;
    int warpM = (w & 1) * 32, warpO = (w >> 1) * 32;
    f32x4 acc[2][2];
    #pragma unroll
    for (int i = 0; i < 2; ++i)
        #pragma unroll
        for (int j = 0; j < 2; ++j) acc[i][j] = (f32x4){0.f, 0.f, 0.f, 0.f};
    int lr = t >> 2;
    int lc = (t & 3) * 8;
    const unsigned short* Xp = X + (size_t)(mBase + lr) * ldx + lc;
    const unsigned short* Wp = W + (size_t)(oBase + lr) * ldw + lc;
    int ar0 = (warpM + (lane & 15)) * 32 + (lane >> 4) * 8;
    int br0 = (warpO + (lane & 15)) * 32 + (lane >> 4) * 8;
    for (int k0 = 0; k0 < K; k0 += 32) {
        uint4 xa = *(const uint4*)(Xp + k0);
        uint4 wb = *(const uint4*)(Wp + k0);
        __syncthreads();
        *(uint4*)&As[lr * 32 + lc] = xa;
        *(uint4*)&Bs[lr * 32 + lc] = wb;
        __syncthreads();
        half8 a0 = __builtin_bit_cast(half8, *(const uint4*)&As[ar0]);
        half8 a1 = __builtin_bit_cast(half8, *(const uint4*)&As[ar0 + 16 * 32]);
        half8 b0 = __builtin_bit_cast(half8, *(const uint4*)&Bs[br0]);
        half8 b1 = __builtin_bit_cast(half8, *(const uint4*)&Bs[br0 + 16 * 32]);
        acc[0][0] = __builtin_amdgcn_mfma_f32_16x16x32_f16(a0, b0, acc[0][0], 0, 0, 0);
        acc[0][1] = __builtin_amdgcn_mfma_f32_16x16x32_f16(a0, b1, acc[0][1], 0, 0, 0);
        acc[1][0] = __builtin_amdgcn_mfma_f32_16x16x32_f16(a1, b0, acc[1][0], 0, 0, 0);
        acc[1][1] = __builtin_amdgcn_mfma_f32_16x16x32_f16(a1, b1, acc[1][1], 0, 0, 0);
    }
    #pragma unroll
    for (int i = 0; i < 2; ++i) {
        #pragma unroll
        for (int j = 0; j < 2; ++j) {
            int m0 = mBase + warpM + i * 16 + (lane >> 4) * 4;
            int o = oBase + warpO + j * 16 + (lane & 15);
            #pragma unroll
            for (int r = 0; r < 4; ++r)
                Y[(size_t)(m0 + r) * Co + o] = acc[i][j][r];
        }
    }
    if (doStats) {
        __syncthreads();  // all LDS reads of last tile done
        float* ssum = (float*)As;
        float* ssq = (float*)Bs;
        if (t < 64) { ssum[t] = 0.f; ssq[t] = 0.f; }
        __syncthreads();
        #pragma unroll
        for (int j = 0; j < 2; ++j) {
            int oc = warpO + j * 16 + (lane & 15);
            float s = 0.f, q = 0.f;
            #pragma unroll
            for (int i = 0; i < 2; ++i)
                #pragma unroll
                for (int r = 0; r < 4; ++r) { float v = acc[i][j][r]; s += v; q += v * v; }
            atomicAdd(&ssum[oc], s);
            atomicAdd(&ssq[oc], q);
        }
        __syncthreads();
        if (t < 64) {
            atomicAdd(&sums[oBase + t], ssum[t]);
            atomicAdd(&sums[1024 + oBase + t], ssq[t]);
        }
    }
}

// ---------------------------------------------------------------------------
// BN stats for pf0 only (fp32 Y, Co=64)
// ---------------------------------------------------------------------------
__global__ __launch_bounds__(256) void bnstat_k(const float* __restrict__ Y, int Co,
                                                float* __restrict__ sums) {
    int o0 = blockIdx.x * 64;
    int m0 = blockIdx.y * 512;
    int t = threadIdx.x, ol = t & 63, mg = t >> 6;
    float s = 0.f, q = 0.f;
    const float* p = Y + (size_t)(m0 + mg) * Co + o0 + ol;
    for (int i = 0; i < 128; ++i) {
        float v = p[(size_t)i * 4 * Co];
        s += v; q += v * v;
    }
    __shared__ float ls[4][64], lq[4][64];
    ls[mg][ol] = s; lq[mg][ol] = q;
    __syncthreads();
    if (mg == 0) {
        s = ls[0][ol] + ls[1][ol] + ls[2][ol] + ls[3][ol];
        q = lq[0][ol] + lq[1][ol] + lq[2][ol] + lq[3][ol];
        atomicAdd(&sums[o0 + ol], s);
        atomicAdd(&sums[1024 + o0 + ol], q);
    }
}

// finalize BN coefficients; re-zero consumed sums for next layer
__global__ void bnfin_k(float* __restrict__ sums, const float* __restrict__ g,
                        const float* __restrict__ bb, float* __restrict__ ab, int Co) {
    int o = blockIdx.x * 256 + threadIdx.x;
    if (o >= Co) return;
    float mu = sums[o] * (1.f / 8192.f);
    float var = sums[1024 + o] * (1.f / 8192.f) - mu * mu;
    var = fmaxf(var, 0.f);
    float a = g[o] / sqrtf(var + EPSF);
    ab[2 * o] = a;
    ab[2 * o + 1] = bb[o] - mu * a;
    sums[o] = 0.f;
    sums[1024 + o] = 0.f;
}

// ---------------------------------------------------------------------------
// BN normalize + ReLU + fp16 store into dest slice (ldd-strided)
// ---------------------------------------------------------------------------
__global__ __launch_bounds__(256) void bnorm_k(const float* __restrict__ Y, const float* __restrict__ ab,
                                               unsigned short* __restrict__ dst, int ldd, int shift) {
    int idx4 = blockIdx.x * 256 + threadIdx.x;
    int m = idx4 >> shift;
    int o4 = idx4 & ((1 << shift) - 1);
    float4 v = ((const float4*)Y)[idx4];
    float4 p0 = *(const float4*)&ab[8 * o4];
    float4 p1 = *(const float4*)&ab[8 * o4 + 4];
    ushort4 u;
    u.x = f2h(fmaxf(v.x * p0.x + p0.y, 0.f));
    u.y = f2h(fmaxf(v.y * p0.z + p0.w, 0.f));
    u.z = f2h(fmaxf(v.z * p1.x + p1.y, 0.f));
    u.w = f2h(fmaxf(v.w * p1.z + p1.w, 0.f));
    *(ushort4*)&dst[(size_t)m * ldd + o4 * 4] = u;
}

// ---------------------------------------------------------------------------
// max over N per (b, channel) from pf3's fp16 slice
// ---------------------------------------------------------------------------
__global__ __launch_bounds__(256) void maxred_k(const unsigned short* __restrict__ Xs,
                                                float* __restrict__ maxbuf) {
    int o0 = blockIdx.x * 64;
    int b = blockIdx.y;
    int rc = blockIdx.z;
    int t = threadIdx.x, ol = t & 63, mg = t >> 6;
    float mx = 0.f;
    for (int i = 0; i < 128; ++i) {
        int m = b * NN + rc * 512 + i * 4 + mg;
        mx = fmaxf(mx, h2f(Xs[(size_t)m * 2400 + o0 + ol]));
    }
    __shared__ float ls[4][64];
    ls[mg][ol] = mx;
    __syncthreads();
    if (mg == 0) {
        mx = fmaxf(fmaxf(ls[0][ol], ls[1][ol]), fmaxf(ls[2][ol], ls[3][ol]));
        atomicMax((unsigned*)&maxbuf[b * 1024 + o0 + ol], __builtin_bit_cast(unsigned, mx));
    }
}

__global__ __launch_bounds__(256) void maxbc_k(const float* __restrict__ maxbuf,
                                               unsigned short* __restrict__ XCb) {
    int idx8 = blockIdx.x * 256 + threadIdx.x;
    int m = idx8 >> 7;
    int o8 = (idx8 & 127) * 8;
    int b = m >> 11;
    const float* mb = maxbuf + b * 1024 + o8;
    ushort4 u0 = make_ushort4(f2h(mb[0]), f2h(mb[1]), f2h(mb[2]), f2h(mb[3]));
    ushort4 u1 = make_ushort4(f2h(mb[4]), f2h(mb[5]), f2h(mb[6]), f2h(mb[7]));
    *(ushort4*)&XCb[(size_t)m * 2400 + 1360 + o8] = u0;
    *(ushort4*)&XCb[(size_t)m * 2400 + 1360 + o8 + 4] = u1;
}

// ---------------------------------------------------------------------------
// final: OT(M,128) fp32 -> out (B,50,N) + bias, via LDS transpose
// ---------------------------------------------------------------------------
__global__ __launch_bounds__(256) void wout_k(const float* __restrict__ OT,
                                              const float* __restrict__ bias,
                                              float* __restrict__ out) {
    __shared__ float ts[128][65];
    int t = threadIdx.x;
    int m0 = blockIdx.x * 128;
    #pragma unroll
    for (int i = 0; i < 8; ++i) {
        int idx4 = t + 256 * i;
        int row = idx4 >> 4, c4 = (idx4 & 15) * 4;
        float4 v = *(const float4*)&OT[(size_t)(m0 + row) * 128 + c4];
        ts[row][c4] = v.x; ts[row][c4 + 1] = v.y; ts[row][c4 + 2] = v.z; ts[row][c4 + 3] = v.w;
    }
    __syncthreads();
    int b = m0 >> 11, n0 = m0 & (NN - 1);
    #pragma unroll
    for (int j = 0; j < 25; ++j) {
        int idx = t + 256 * j;
        int o = idx >> 7, nl = idx & 127;
        out[((size_t)b * 50 + o) * NN + n0 + nl] = ts[nl][o] + bias[o];
    }
}

// ---------------------------------------------------------------------------
extern "C" void kernel_launch(void* const* d_in, const int* in_sizes, int n_in,
                              void* d_out, int out_size, void* d_ws, size_t ws_size,
                              hipStream_t stream) {
    const float* in = (const float*)d_in[0];
    const float* pf0_w = (const float*)d_in[1];
    const float* pf_g[4] = {(const float*)d_in[2], (const float*)d_in[5], (const float*)d_in[8], (const float*)d_in[11]};
    const float* pf_b[4] = {(const float*)d_in[3], (const float*)d_in[6], (const float*)d_in[9], (const float*)d_in[12]};
    const float* pf_w[4] = {(const float*)d_in[1], (const float*)d_in[4], (const float*)d_in[7], (const float*)d_in[10]};
    const float* cls_w[3] = {(const float*)d_in[13], (const float*)d_in[16], (const float*)d_in[19]};
    const float* cls_g[3] = {(const float*)d_in[14], (const float*)d_in[17], (const float*)d_in[20]};
    const float* cls_b[3] = {(const float*)d_in[15], (const float*)d_in[18], (const float*)d_in[21]};
    const float* cls3_w = (const float*)d_in[22];
    const float* cls3_bias = (const float*)d_in[23];
    float* out = (float*)d_out;

    char* wsb = (char*)d_ws;
    float* ST = (float*)(wsb + 0);
    float* P = (float*)(wsb + 256);
    float* F0 = (float*)(wsb + 98560);
    float* SUMS = (float*)(wsb + 262400);
    float* MAXB = (float*)(wsb + 270592);
    float* AB = (float*)(wsb + 286976);
    unsigned short* WB = (unsigned short*)(wsb + 295168);
    unsigned short* XCb = (unsigned short*)(wsb + 2064640);
    unsigned short* C1b = (unsigned short*)(wsb + 41386240);
    unsigned short* C2b = (unsigned short*)(wsb + 45580544);
    unsigned short* C3b = (unsigned short*)(wsb + 49774848);
    float* Y = (float*)(wsb + 51872000);

    zero_k<<<24, 256, 0, stream>>>(SUMS);  // SUMS (2048) + MAXB (4096)
    wconv_k<<<3456, 256, 0, stream>>>(pf_w[1], pf_w[2], pf_w[3], cls_w[0], cls_w[1], cls_w[2], cls3_w, WB);
    stats_k<<<BB, 256, 0, stream>>>(in, ST);
    point_k<<<MM / 256, 256, 0, stream>>>(in, ST, P, F0);
    alpha_k<<<BB * NN / 8, 256, 0, stream>>>(P, F0);
    onehot_k<<<MM / 256, 256, 0, stream>>>(in, XCb);

    auto bn = [&](int Co, const float* g, const float* bbias, unsigned short* dst, int ldd, int shift) {
        bnfin_k<<<(Co + 255) / 256, 256, 0, stream>>>(SUMS, g, bbias, AB, Co);
        bnorm_k<<<8 * Co, 256, 0, stream>>>(Y, AB, dst, ldd, shift);
    };

    // pf0 (fp32 path; stats via small bnstat)
    pf0_k<<<MM / 256, 256, 0, stream>>>(F0, pf0_w, Y);
    bnstat_k<<<dim3(1, 16), 256, 0, stream>>>(Y, 64, SUMS);
    bn(64, pf_g[0], pf_b[0], XCb + 16, 2400, 4);
    // pf1
    mgemm_k<<<dim3(128, 2), 256, 0, stream>>>(XCb + 16, 2400, WB, 64, Y, 128, 64, SUMS, 1);
    bn(128, pf_g[1], pf_b[1], XCb + 80, 2400, 5);
    // pf2
    mgemm_k<<<dim3(128, 2), 256, 0, stream>>>(XCb + 80, 2400, WB + 8192, 128, Y, 128, 128, SUMS, 1);
    bn(128, pf_g[2], pf_b[2], XCb + 208, 2400, 5);
    // pf3
    mgemm_k<<<dim3(128, 16), 256, 0, stream>>>(XCb + 208, 2400, WB + 24576, 128, Y, 1024, 128, SUMS, 1);
    bn(1024, pf_g[3], pf_b[3], XCb + 336, 2400, 8);
    // max feature
    maxred_k<<<dim3(16, 4, 4), 256, 0, stream>>>(XCb + 336, MAXB);
    maxbc_k<<<4096, 256, 0, stream>>>(MAXB, XCb);
    // cls0
    mgemm_k<<<dim3(128, 4), 256, 0, stream>>>(XCb, 2400, WB + 155648, 2400, Y, 256, 2400, SUMS, 1);
    bn(256, cls_g[0], cls_b[0], C1b, 256, 6);
    // cls1
    mgemm_k<<<dim3(128, 4), 256, 0, stream>>>(C1b, 256, WB + 770048, 256, Y, 256, 256, SUMS, 1);
    bn(256, cls_g[1], cls_b[1], C2b, 256, 6);
    // cls2
    mgemm_k<<<dim3(128, 2), 256, 0, stream>>>(C2b, 256, WB + 835584, 256, Y, 128, 256, SUMS, 1);
    bn(128, cls_g[2], cls_b[2], C3b, 128, 5);
    // cls3 (padded to 128 outputs, rows 50..127 zero)
    mgemm_k<<<dim3(128, 2), 256, 0, stream>>>(C3b, 128, WB + 868352, 128, Y, 128, 128, SUMS, 0);
    wout_k<<<MM / 128, 256, 0, stream>>>(Y, cls3_bias, out);

    (void)in_sizes; (void)n_in; (void)out_size; (void)ws_size;
}

// Round 5
// 282.396 us; speedup vs baseline: 2.4287x; 1.0149x over previous
//
#include <hip/hip_runtime.h>
#include <math.h>

#define BB 4
#define NN 2048
#define MM 8192
#define EPSF 1e-5f

typedef _Float16 half8 __attribute__((ext_vector_type(8)));
typedef float f32x4 __attribute__((ext_vector_type(4)));

__device__ __forceinline__ unsigned short f2h(float x) {
    _Float16 h = (_Float16)x;
    return __builtin_bit_cast(unsigned short, h);
}
__device__ __forceinline__ float h2f(unsigned short u) {
    return (float)__builtin_bit_cast(_Float16, u);
}

// ---------------------------------------------------------------------------
// per-batch stats: cc, cn, ncn
// ---------------------------------------------------------------------------
__global__ __launch_bounds__(256) void stats_k(const float* __restrict__ in,
                                               float* __restrict__ st) {
    int b = blockIdx.x;
    int t = threadIdx.x;
    const float* base = in + (size_t)b * 22 * NN;
    float cs0 = 0.f, cs1 = 0.f, cs2 = 0.f, ns0 = 0.f, ns1 = 0.f, ns2 = 0.f;
    for (int n = t; n < NN; n += 256) {
        float cx = base[0 * NN + n], cy = base[1 * NN + n], cz = base[2 * NN + n];
        float nx = base[3 * NN + n], ny = base[4 * NN + n], nz = base[5 * NN + n];
        float inv = 1.0f / sqrtf(nx * nx + ny * ny + nz * nz);
        cs0 += cx; cs1 += cy; cs2 += cz;
        ns0 += nx * inv; ns1 += ny * inv; ns2 += nz * inv;
    }
    __shared__ float red[6][256];
    red[0][t] = cs0; red[1][t] = cs1; red[2][t] = cs2;
    red[3][t] = ns0; red[4][t] = ns1; red[5][t] = ns2;
    __syncthreads();
    for (int s = 128; s > 0; s >>= 1) {
        if (t < s) {
            #pragma unroll
            for (int i = 0; i < 6; ++i) red[i][t] += red[i][t + s];
        }
        __syncthreads();
    }
    if (t == 0) {
        float ccx = red[0][0] / (float)NN, ccy = red[1][0] / (float)NN, ccz = red[2][0] / (float)NN;
        float cnx = red[3][0] / (float)NN, cny = red[4][0] / (float)NN, cnz = red[5][0] / (float)NN;
        float inv = 1.0f / sqrtf(cnx * cnx + cny * cny + cnz * cnz);
        float* s9 = st + b * 16;
        s9[0] = ccx; s9[1] = ccy; s9[2] = ccz;
        s9[3] = cnx; s9[4] = cny; s9[5] = cnz;
        s9[6] = cnx * inv; s9[7] = cny * inv; s9[8] = cnz * inv;
    }
}

__device__ __forceinline__ float angle3(float ux, float uy, float uz,
                                        float vx, float vy, float vz) {
    float crx = uy * vz - uz * vy;
    float cry = uz * vx - ux * vz;
    float crz = ux * vy - uy * vx;
    float s = sqrtf(crx * crx + cry * cry + crz * crz);
    float c = ux * vx + uy * vy + uz * vz;
    return atan2f(s, c);
}

// ---------------------------------------------------------------------------
// per-point PPF (F0 rows 0..3) + packed projected vectors PQ = (x,y,z,|P|)
// ---------------------------------------------------------------------------
__global__ __launch_bounds__(256) void point_k(const float* __restrict__ in,
                                               const float* __restrict__ st,
                                               float4* __restrict__ PQ,
                                               float* __restrict__ F0) {
    int idx = blockIdx.x * 256 + threadIdx.x;
    int b = idx >> 11, n = idx & (NN - 1);
    const float* base = in + (size_t)b * 22 * NN;
    const float* s9 = st + b * 16;
    float cx = base[0 * NN + n], cy = base[1 * NN + n], cz = base[2 * NN + n];
    float nx = base[3 * NN + n], ny = base[4 * NN + n], nz = base[5 * NN + n];
    float inv = 1.0f / sqrtf(nx * nx + ny * ny + nz * nz);
    nx *= inv; ny *= inv; nz *= inv;
    float ccx = s9[0], ccy = s9[1], ccz = s9[2];
    float cnx = s9[3], cny = s9[4], cnz = s9[5];
    float ex = s9[6], ey = s9[7], ez = s9[8];
    float dx = cx - ccx, dy = cy - ccy, dz = cz - ccz;
    F0[0 * MM + idx] = angle3(cnx, cny, cnz, dx, dy, dz);
    F0[1 * MM + idx] = angle3(nx, ny, nz, dx, dy, dz);
    F0[2 * MM + idx] = angle3(cnx, cny, cnz, nx, ny, nz);
    F0[3 * MM + idx] = sqrtf(dx * dx + dy * dy + dz * dz);
    float dot = dx * ex + dy * ey + dz * ez;
    float px = dx - dot * cnx;
    float py = dy - dot * cny;
    float pz = dz - dot * cnz;
    PQ[idx] = make_float4(px, py, pz, sqrtf(px * px + py * py + pz * pz));
}

// ---------------------------------------------------------------------------
// per-row median of pairwise angles. One ROW PER WAVE (max occupancy, no
// LDS). Monotone key = tan^2(theta/2) = ss/(c+|a||b|)^2; key<=2.5e-11 -> +INF
// (matches reference's at<=1e-5 -> 100, sorts last). 20-bit MSB radix select
// via __ballot; value reconstructed once per row as 2*atan(sqrt(key)).
// Columns read directly from PQ (L1/L2-resident, 32KB per batch).
// ---------------------------------------------------------------------------
__global__ __launch_bounds__(256) void alpha_k(const float4* __restrict__ PQ,
                                               float* __restrict__ F0) {
    int row = blockIdx.x * 4 + (threadIdx.x >> 6);
    int lane = threadIdx.x & 63;
    int b = row >> 11;
    const float4* base = PQ + (size_t)b * NN;
    float4 a = base[row & (NN - 1)];
    unsigned u[32];
    #pragma unroll
    for (int s2 = 0; s2 < 32; ++s2) {
        float4 bv = base[s2 * 64 + lane];
        float crx = a.y * bv.z - a.z * bv.y;
        float cry = a.z * bv.x - a.x * bv.z;
        float crz = a.x * bv.y - a.y * bv.x;
        float ss = crx * crx + cry * cry + crz * crz;
        float c = a.x * bv.x + a.y * bv.y + a.z * bv.z;
        float den = c + a.w * bv.w;
        float rc = __builtin_amdgcn_rcpf(den);
        float key = ss * rc * rc;
        if (key <= 2.5e-11f) key = __builtin_inff();
        u[s2] = __float_as_uint(key);
    }
    unsigned p = 0u;
    int k = 1023;
    for (int bit = 30; bit >= 11; --bit) {
        unsigned thr = 1u << bit;
        int cnt = 0;
        #pragma unroll
        for (int s2 = 0; s2 < 32; ++s2)
            cnt += (int)__popcll(__ballot((u[s2] ^ p) < thr));
        if (k >= cnt) { k -= cnt; p |= thr; }
    }
    if (lane == 0)
        F0[4 * MM + row] = 2.0f * atanf(sqrtf(__uint_as_float(p)));
}

// ---------------------------------------------------------------------------
// zero a small region (SUMS + MAXB)
// ---------------------------------------------------------------------------
__global__ void zero_k(float* __restrict__ p) {
    p[blockIdx.x * 256 + threadIdx.x] = 0.f;
}

// ---------------------------------------------------------------------------
// convert all weights to fp16 (K-pad for cls0, O-pad for cls3)
// ---------------------------------------------------------------------------
__global__ __launch_bounds__(256) void wconv_k(const float* __restrict__ w1, const float* __restrict__ w2,
                                               const float* __restrict__ w3, const float* __restrict__ w4,
                                               const float* __restrict__ w5, const float* __restrict__ w6,
                                               const float* __restrict__ w7, unsigned short* __restrict__ Wb) {
    int idx = blockIdx.x * 256 + threadIdx.x;
    unsigned short v;
    if (idx < 8192) v = f2h(w1[idx]);
    else if (idx < 24576) v = f2h(w2[idx - 8192]);
    else if (idx < 155648) v = f2h(w3[idx - 24576]);
    else if (idx < 770048) {
        int l = idx - 155648;
        int o = l / 2400, k = l - o * 2400;
        v = (k < 2384) ? f2h(w4[o * 2384 + k]) : (unsigned short)0;
    } else if (idx < 835584) v = f2h(w5[idx - 770048]);
    else if (idx < 868352) v = f2h(w6[idx - 835584]);
    else {
        int l = idx - 868352;
        int o = l >> 7, k = l & 127;
        v = (o < 50) ? f2h(w7[o * 128 + k]) : (unsigned short)0;
    }
    Wb[idx] = v;
}

// ---------------------------------------------------------------------------
// one-hot rows 0..15 of XCb + zero pad cols 2384..2399
// ---------------------------------------------------------------------------
__global__ __launch_bounds__(256) void onehot_k(const float* __restrict__ in,
                                                unsigned short* __restrict__ XCb) {
    int m = blockIdx.x * 256 + threadIdx.x;
    int b = m >> 11, n = m & (NN - 1);
    const float* src = in + (size_t)b * 22 * NN + 6 * NN + n;
    unsigned short vals[16];
    #pragma unroll
    for (int r = 0; r < 16; ++r) vals[r] = f2h(src[(size_t)r * NN]);
    ushort4* dst = (ushort4*)&XCb[(size_t)m * 2400];
    #pragma unroll
    for (int q = 0; q < 4; ++q)
        dst[q] = make_ushort4(vals[4 * q], vals[4 * q + 1], vals[4 * q + 2], vals[4 * q + 3]);
    ushort4 z = make_ushort4(0, 0, 0, 0);
    ushort4* pz = (ushort4*)&XCb[(size_t)m * 2400 + 2384];
    pz[0] = z; pz[1] = z; pz[2] = z; pz[3] = z;
}

// ---------------------------------------------------------------------------
// pf0: tiny K=5 GEMM, Y (M,64) fp32
// ---------------------------------------------------------------------------
__global__ __launch_bounds__(256) void pf0_k(const float* __restrict__ F0,
                                             const float* __restrict__ W,
                                             float* __restrict__ Y) {
    __shared__ float ws[320];
    int t = threadIdx.x;
    for (int i = t; i < 320; i += 256) ws[i] = W[i];
    __syncthreads();
    int m = blockIdx.x * 256 + t;
    float x0 = F0[m], x1 = F0[MM + m], x2 = F0[2 * MM + m], x3 = F0[3 * MM + m], x4 = F0[4 * MM + m];
    float* ym = Y + (size_t)m * 64;
    #pragma unroll
    for (int o = 0; o < 64; ++o) {
        const float* wo = &ws[o * 5];
        ym[o] = wo[0] * x0 + wo[1] * x1 + wo[2] * x2 + wo[3] * x3 + wo[4] * x4;
    }
}

// ---------------------------------------------------------------------------
// fp16 MFMA GEMM (64x64 tile, 4 waves, wave=32x32): small layers.
// Optional fused BN-stat epilogue.
// ---------------------------------------------------------------------------
__global__ __launch_bounds__(256) void mgemm_k(const unsigned short* __restrict__ X, int ldx,
                                               const unsigned short* __restrict__ W, int ldw,
                                               float* __restrict__ Y, int Co, int K,
                                               float* __restrict__ sums, int doStats) {
    __shared__ unsigned short As[64 * 32];
    __shared__ unsigned short Bs[64 * 32];
    int t = threadIdx.x;
    int mBase = blockIdx.x * 64;
    int oBase = blockIdx.y * 64;
    int lane = t & 63, w = t >> 6;
    int warpM = (w & 1) * 32, warpO = (w >> 1) * 32;
    f32x4 acc[2][2];
    #pragma unroll
    for (int i = 0; i < 2; ++i)
        #pragma unroll
        for (int j = 0; j < 2; ++j) acc[i][j] = (f32x4){0.f, 0.f, 0.f, 0.f};
    int lr = t >> 2;
    int lc = (t & 3) * 8;
    const unsigned short* Xp = X + (size_t)(mBase + lr) * ldx + lc;
    const unsigned short* Wp = W + (size_t)(oBase + lr) * ldw + lc;
    int ar0 = (warpM + (lane & 15)) * 32 + (lane >> 4) * 8;
    int br0 = (warpO + (lane & 15)) * 32 + (lane >> 4) * 8;
    for (int k0 = 0; k0 < K; k0 += 32) {
        uint4 xa = *(const uint4*)(Xp + k0);
        uint4 wb = *(const uint4*)(Wp + k0);
        __syncthreads();
        *(uint4*)&As[lr * 32 + lc] = xa;
        *(uint4*)&Bs[lr * 32 + lc] = wb;
        __syncthreads();
        half8 a0 = __builtin_bit_cast(half8, *(const uint4*)&As[ar0]);
        half8 a1 = __builtin_bit_cast(half8, *(const uint4*)&As[ar0 + 16 * 32]);
        half8 b0 = __builtin_bit_cast(half8, *(const uint4*)&Bs[br0]);
        half8 b1 = __builtin_bit_cast(half8, *(const uint4*)&Bs[br0 + 16 * 32]);
        acc[0][0] = __builtin_amdgcn_mfma_f32_16x16x32_f16(a0, b0, acc[0][0], 0, 0, 0);
        acc[0][1] = __builtin_amdgcn_mfma_f32_16x16x32_f16(a0, b1, acc[0][1], 0, 0, 0);
        acc[1][0] = __builtin_amdgcn_mfma_f32_16x16x32_f16(a1, b0, acc[1][0], 0, 0, 0);
        acc[1][1] = __builtin_amdgcn_mfma_f32_16x16x32_f16(a1, b1, acc[1][1], 0, 0, 0);
    }
    #pragma unroll
    for (int i = 0; i < 2; ++i) {
        #pragma unroll
        for (int j = 0; j < 2; ++j) {
            int m0 = mBase + warpM + i * 16 + (lane >> 4) * 4;
            int o = oBase + warpO + j * 16 + (lane & 15);
            #pragma unroll
            for (int r = 0; r < 4; ++r)
                Y[(size_t)(m0 + r) * Co + o] = acc[i][j][r];
        }
    }
    if (doStats) {
        __syncthreads();
        float* ssum = (float*)As;
        float* ssq = (float*)Bs;
        if (t < 64) { ssum[t] = 0.f; ssq[t] = 0.f; }
        __syncthreads();
        #pragma unroll
        for (int j = 0; j < 2; ++j) {
            int oc = warpO + j * 16 + (lane & 15);
            float s = 0.f, q = 0.f;
            #pragma unroll
            for (int i = 0; i < 2; ++i)
                #pragma unroll
                for (int r = 0; r < 4; ++r) { float v = acc[i][j][r]; s += v; q += v * v; }
            atomicAdd(&ssum[oc], s);
            atomicAdd(&ssq[oc], q);
        }
        __syncthreads();
        if (t < 64) {
            atomicAdd(&sums[oBase + t], ssum[t]);
            atomicAdd(&sums[1024 + oBase + t], ssq[t]);
        }
    }
}

// ---------------------------------------------------------------------------
// fp16 MFMA GEMM, wide-O tile: BM=64, BO=128, 4 waves, wave=32x64 (2x4 frags,
// 8 MFMA : 6 ds_read_b128). For the big layers (pf3, cls0).
// ---------------------------------------------------------------------------
__global__ __launch_bounds__(256) void mgemm2_k(const unsigned short* __restrict__ X, int ldx,
                                                const unsigned short* __restrict__ W, int ldw,
                                                float* __restrict__ Y, int Co, int K,
                                                float* __restrict__ sums, int doStats) {
    __shared__ unsigned short As[64 * 32];    // 4KB
    __shared__ unsigned short Bs[128 * 32];   // 8KB
    int t = threadIdx.x;
    int mBase = blockIdx.x * 64;
    int oBase = blockIdx.y * 128;
    int lane = t & 63, w = t >> 6;
    int warpM = (w & 1) * 32, warpO = (w >> 1) * 64;
    f32x4 acc[2][4];
    #pragma unroll
    for (int i = 0; i < 2; ++i)
        #pragma unroll
        for (int j = 0; j < 4; ++j) acc[i][j] = (f32x4){0.f, 0.f, 0.f, 0.f};
    int lr = t >> 2;
    int lc = (t & 3) * 8;
    const unsigned short* Xp = X + (size_t)(mBase + lr) * ldx + lc;
    const unsigned short* Wp0 = W + (size_t)(oBase + lr) * ldw + lc;
    const unsigned short* Wp1 = W + (size_t)(oBase + lr + 64) * ldw + lc;
    int ar0 = (warpM + (lane & 15)) * 32 + (lane >> 4) * 8;
    int br0 = (warpO + (lane & 15)) * 32 + (lane >> 4) * 8;
    for (int k0 = 0; k0 < K; k0 += 32) {
        uint4 xa = *(const uint4*)(Xp + k0);
        uint4 wb0 = *(const uint4*)(Wp0 + k0);
        uint4 wb1 = *(const uint4*)(Wp1 + k0);
        __syncthreads();
        *(uint4*)&As[lr * 32 + lc] = xa;
        *(uint4*)&Bs[lr * 32 + lc] = wb0;
        *(uint4*)&Bs[(lr + 64) * 32 + lc] = wb1;
        __syncthreads();
        half8 a0 = __builtin_bit_cast(half8, *(const uint4*)&As[ar0]);
        half8 a1 = __builtin_bit_cast(half8, *(const uint4*)&As[ar0 + 16 * 32]);
        half8 b0 = __builtin_bit_cast(half8, *(const uint4*)&Bs[br0]);
        half8 b1 = __builtin_bit_cast(half8, *(const uint4*)&Bs[br0 + 16 * 32]);
        half8 b2 = __builtin_bit_cast(half8, *(const uint4*)&Bs[br0 + 32 * 32]);
        half8 b3 = __builtin_bit_cast(half8, *(const uint4*)&Bs[br0 + 48 * 32]);
        acc[0][0] = __builtin_amdgcn_mfma_f32_16x16x32_f16(a0, b0, acc[0][0], 0, 0, 0);
        acc[0][1] = __builtin_amdgcn_mfma_f32_16x16x32_f16(a0, b1, acc[0][1], 0, 0, 0);
        acc[0][2] = __builtin_amdgcn_mfma_f32_16x16x32_f16(a0, b2, acc[0][2], 0, 0, 0);
        acc[0][3] = __builtin_amdgcn_mfma_f32_16x16x32_f16(a0, b3, acc[0][3], 0, 0, 0);
        acc[1][0] = __builtin_amdgcn_mfma_f32_16x16x32_f16(a1, b0, acc[1][0], 0, 0, 0);
        acc[1][1] = __builtin_amdgcn_mfma_f32_16x16x32_f16(a1, b1, acc[1][1], 0, 0, 0);
        acc[1][2] = __builtin_amdgcn_mfma_f32_16x16x32_f16(a1, b2, acc[1][2], 0, 0, 0);
        acc[1][3] = __builtin_amdgcn_mfma_f32_16x16x32_f16(a1, b3, acc[1][3], 0, 0, 0);
    }
    #pragma unroll
    for (int i = 0; i < 2; ++i) {
        #pragma unroll
        for (int j = 0; j < 4; ++j) {
            int m0 = mBase + warpM + i * 16 + (lane >> 4) * 4;
            int o = oBase + warpO + j * 16 + (lane & 15);
            #pragma unroll
            for (int r = 0; r < 4; ++r)
                Y[(size_t)(m0 + r) * Co + o] = acc[i][j][r];
        }
    }
    if (doStats) {
        __syncthreads();
        float* ssum = (float*)As;
        float* ssq = (float*)Bs;
        if (t < 128) { ssum[t] = 0.f; ssq[t] = 0.f; }
        __syncthreads();
        #pragma unroll
        for (int j = 0; j < 4; ++j) {
            int oc = warpO + j * 16 + (lane & 15);
            float s = 0.f, q = 0.f;
            #pragma unroll
            for (int i = 0; i < 2; ++i)
                #pragma unroll
                for (int r = 0; r < 4; ++r) { float v = acc[i][j][r]; s += v; q += v * v; }
            atomicAdd(&ssum[oc], s);
            atomicAdd(&ssq[oc], q);
        }
        __syncthreads();
        if (t < 128) {
            atomicAdd(&sums[oBase + t], ssum[t]);
            atomicAdd(&sums[1024 + oBase + t], ssq[t]);
        }
    }
}

// ---------------------------------------------------------------------------
// BN stats for pf0 only (fp32 Y, Co=64)
// ---------------------------------------------------------------------------
__global__ __launch_bounds__(256) void bnstat_k(const float* __restrict__ Y, int Co,
                                                float* __restrict__ sums) {
    int o0 = blockIdx.x * 64;
    int m0 = blockIdx.y * 512;
    int t = threadIdx.x, ol = t & 63, mg = t >> 6;
    float s = 0.f, q = 0.f;
    const float* p = Y + (size_t)(m0 + mg) * Co + o0 + ol;
    for (int i = 0; i < 128; ++i) {
        float v = p[(size_t)i * 4 * Co];
        s += v; q += v * v;
    }
    __shared__ float ls[4][64], lq[4][64];
    ls[mg][ol] = s; lq[mg][ol] = q;
    __syncthreads();
    if (mg == 0) {
        s = ls[0][ol] + ls[1][ol] + ls[2][ol] + ls[3][ol];
        q = lq[0][ol] + lq[1][ol] + lq[2][ol] + lq[3][ol];
        atomicAdd(&sums[o0 + ol], s);
        atomicAdd(&sums[1024 + o0 + ol], q);
    }
}

// finalize BN coefficients; re-zero consumed sums for next layer
__global__ void bnfin_k(float* __restrict__ sums, const float* __restrict__ g,
                        const float* __restrict__ bb, float* __restrict__ ab, int Co) {
    int o = blockIdx.x * 256 + threadIdx.x;
    if (o >= Co) return;
    float mu = sums[o] * (1.f / 8192.f);
    float var = sums[1024 + o] * (1.f / 8192.f) - mu * mu;
    var = fmaxf(var, 0.f);
    float a = g[o] / sqrtf(var + EPSF);
    ab[2 * o] = a;
    ab[2 * o + 1] = bb[o] - mu * a;
    sums[o] = 0.f;
    sums[1024 + o] = 0.f;
}

// ---------------------------------------------------------------------------
// BN normalize + ReLU + fp16 store into dest slice (ldd-strided)
// ---------------------------------------------------------------------------
__global__ __launch_bounds__(256) void bnorm_k(const float* __restrict__ Y, const float* __restrict__ ab,
                                               unsigned short* __restrict__ dst, int ldd, int shift) {
    int idx4 = blockIdx.x * 256 + threadIdx.x;
    int m = idx4 >> shift;
    int o4 = idx4 & ((1 << shift) - 1);
    float4 v = ((const float4*)Y)[idx4];
    float4 p0 = *(const float4*)&ab[8 * o4];
    float4 p1 = *(const float4*)&ab[8 * o4 + 4];
    ushort4 u;
    u.x = f2h(fmaxf(v.x * p0.x + p0.y, 0.f));
    u.y = f2h(fmaxf(v.y * p0.z + p0.w, 0.f));
    u.z = f2h(fmaxf(v.z * p1.x + p1.y, 0.f));
    u.w = f2h(fmaxf(v.w * p1.z + p1.w, 0.f));
    *(ushort4*)&dst[(size_t)m * ldd + o4 * 4] = u;
}

// ---------------------------------------------------------------------------
// max over N per (b, channel) from pf3's fp16 slice
// ---------------------------------------------------------------------------
__global__ __launch_bounds__(256) void maxred_k(const unsigned short* __restrict__ Xs,
                                                float* __restrict__ maxbuf) {
    int o0 = blockIdx.x * 64;
    int b = blockIdx.y;
    int rc = blockIdx.z;
    int t = threadIdx.x, ol = t & 63, mg = t >> 6;
    float mx = 0.f;
    for (int i = 0; i < 128; ++i) {
        int m = b * NN + rc * 512 + i * 4 + mg;
        mx = fmaxf(mx, h2f(Xs[(size_t)m * 2400 + o0 + ol]));
    }
    __shared__ float ls[4][64];
    ls[mg][ol] = mx;
    __syncthreads();
    if (mg == 0) {
        mx = fmaxf(fmaxf(ls[0][ol], ls[1][ol]), fmaxf(ls[2][ol], ls[3][ol]));
        atomicMax((unsigned*)&maxbuf[b * 1024 + o0 + ol], __builtin_bit_cast(unsigned, mx));
    }
}

__global__ __launch_bounds__(256) void maxbc_k(const float* __restrict__ maxbuf,
                                               unsigned short* __restrict__ XCb) {
    int idx8 = blockIdx.x * 256 + threadIdx.x;
    int m = idx8 >> 7;
    int o8 = (idx8 & 127) * 8;
    int b = m >> 11;
    const float* mb = maxbuf + b * 1024 + o8;
    ushort4 u0 = make_ushort4(f2h(mb[0]), f2h(mb[1]), f2h(mb[2]), f2h(mb[3]));
    ushort4 u1 = make_ushort4(f2h(mb[4]), f2h(mb[5]), f2h(mb[6]), f2h(mb[7]));
    *(ushort4*)&XCb[(size_t)m * 2400 + 1360 + o8] = u0;
    *(ushort4*)&XCb[(size_t)m * 2400 + 1360 + o8 + 4] = u1;
}

// ---------------------------------------------------------------------------
// final: OT(M,128) fp32 -> out (B,50,N) + bias, via LDS transpose
// ---------------------------------------------------------------------------
__global__ __launch_bounds__(256) void wout_k(const float* __restrict__ OT,
                                              const float* __restrict__ bias,
                                              float* __restrict__ out) {
    __shared__ float ts[128][65];
    int t = threadIdx.x;
    int m0 = blockIdx.x * 128;
    #pragma unroll
    for (int i = 0; i < 8; ++i) {
        int idx4 = t + 256 * i;
        int row = idx4 >> 4, c4 = (idx4 & 15) * 4;
        float4 v = *(const float4*)&OT[(size_t)(m0 + row) * 128 + c4];
        ts[row][c4] = v.x; ts[row][c4 + 1] = v.y; ts[row][c4 + 2] = v.z; ts[row][c4 + 3] = v.w;
    }
    __syncthreads();
    int b = m0 >> 11, n0 = m0 & (NN - 1);
    #pragma unroll
    for (int j = 0; j < 25; ++j) {
        int idx = t + 256 * j;
        int o = idx >> 7, nl = idx & 127;
        out[((size_t)b * 50 + o) * NN + n0 + nl] = ts[nl][o] + bias[o];
    }
}

// ---------------------------------------------------------------------------
extern "C" void kernel_launch(void* const* d_in, const int* in_sizes, int n_in,
                              void* d_out, int out_size, void* d_ws, size_t ws_size,
                              hipStream_t stream) {
    const float* in = (const float*)d_in[0];
    const float* pf0_w = (const float*)d_in[1];
    const float* pf_g[4] = {(const float*)d_in[2], (const float*)d_in[5], (const float*)d_in[8], (const float*)d_in[11]};
    const float* pf_b[4] = {(const float*)d_in[3], (const float*)d_in[6], (const float*)d_in[9], (const float*)d_in[12]};
    const float* pf_w[4] = {(const float*)d_in[1], (const float*)d_in[4], (const float*)d_in[7], (const float*)d_in[10]};
    const float* cls_w[3] = {(const float*)d_in[13], (const float*)d_in[16], (const float*)d_in[19]};
    const float* cls_g[3] = {(const float*)d_in[14], (const float*)d_in[17], (const float*)d_in[20]};
    const float* cls_b[3] = {(const float*)d_in[15], (const float*)d_in[18], (const float*)d_in[21]};
    const float* cls3_w = (const float*)d_in[22];
    const float* cls3_bias = (const float*)d_in[23];
    float* out = (float*)d_out;

    char* wsb = (char*)d_ws;
    float* ST = (float*)(wsb + 0);                    // 256 B
    float4* PQ = (float4*)(wsb + 256);                // 131072 B
    float* F0 = (float*)(wsb + 131328);               // 163840 B
    float* SUMS = (float*)(wsb + 295168);             // 8192 B
    float* MAXB = (float*)(wsb + 303360);             // 16384 B
    float* AB = (float*)(wsb + 319744);               // 8192 B
    unsigned short* WB = (unsigned short*)(wsb + 327936);   // 1769472 B
    unsigned short* XCb = (unsigned short*)(wsb + 2097408); // 39321600 B
    unsigned short* C1b = (unsigned short*)(wsb + 41419008); // 4194304 B (reused as C3b)
    unsigned short* C2b = (unsigned short*)(wsb + 45613312); // 4194304 B
    unsigned short* C3b = C1b;                               // C1b dead before cls2's bnorm
    float* Y = (float*)(wsb + 49807616);              // 33554432 B -> ends 83362048

    zero_k<<<24, 256, 0, stream>>>(SUMS);  // SUMS (2048) + MAXB (4096), contiguous
    wconv_k<<<3456, 256, 0, stream>>>(pf_w[1], pf_w[2], pf_w[3], cls_w[0], cls_w[1], cls_w[2], cls3_w, WB);
    stats_k<<<BB, 256, 0, stream>>>(in, ST);
    point_k<<<MM / 256, 256, 0, stream>>>(in, ST, PQ, F0);
    alpha_k<<<MM / 4, 256, 0, stream>>>(PQ, F0);
    onehot_k<<<MM / 256, 256, 0, stream>>>(in, XCb);

    auto bn = [&](int Co, const float* g, const float* bbias, unsigned short* dst, int ldd, int shift) {
        bnfin_k<<<(Co + 255) / 256, 256, 0, stream>>>(SUMS, g, bbias, AB, Co);
        bnorm_k<<<8 * Co, 256, 0, stream>>>(Y, AB, dst, ldd, shift);
    };

    // pf0 (fp32 path; stats via small bnstat)
    pf0_k<<<MM / 256, 256, 0, stream>>>(F0, pf0_w, Y);
    bnstat_k<<<dim3(1, 16), 256, 0, stream>>>(Y, 64, SUMS);
    bn(64, pf_g[0], pf_b[0], XCb + 16, 2400, 4);
    // pf1
    mgemm_k<<<dim3(128, 2), 256, 0, stream>>>(XCb + 16, 2400, WB, 64, Y, 128, 64, SUMS, 1);
    bn(128, pf_g[1], pf_b[1], XCb + 80, 2400, 5);
    // pf2
    mgemm_k<<<dim3(128, 2), 256, 0, stream>>>(XCb + 80, 2400, WB + 8192, 128, Y, 128, 128, SUMS, 1);
    bn(128, pf_g[2], pf_b[2], XCb + 208, 2400, 5);
    // pf3 (wide-O)
    mgemm2_k<<<dim3(128, 8), 256, 0, stream>>>(XCb + 208, 2400, WB + 24576, 128, Y, 1024, 128, SUMS, 1);
    bn(1024, pf_g[3], pf_b[3], XCb + 336, 2400, 8);
    // max feature
    maxred_k<<<dim3(16, 4, 4), 256, 0, stream>>>(XCb + 336, MAXB);
    maxbc_k<<<4096, 256, 0, stream>>>(MAXB, XCb);
    // cls0 (wide-O)
    mgemm2_k<<<dim3(128, 2), 256, 0, stream>>>(XCb, 2400, WB + 155648, 2400, Y, 256, 2400, SUMS, 1);
    bn(256, cls_g[0], cls_b[0], C1b, 256, 6);
    // cls1
    mgemm_k<<<dim3(128, 4), 256, 0, stream>>>(C1b, 256, WB + 770048, 256, Y, 256, 256, SUMS, 1);
    bn(256, cls_g[1], cls_b[1], C2b, 256, 6);
    // cls2
    mgemm_k<<<dim3(128, 2), 256, 0, stream>>>(C2b, 256, WB + 835584, 256, Y, 128, 256, SUMS, 1);
    bn(128, cls_g[2], cls_b[2], C3b, 128, 5);
    // cls3 (padded to 128 outputs, rows 50..127 zero)
    mgemm_k<<<dim3(128, 2), 256, 0, stream>>>(C3b, 128, WB + 868352, 128, Y, 128, 128, SUMS, 0);
    wout_k<<<MM / 128, 256, 0, stream>>>(Y, cls3_bias, out);

    (void)in_sizes; (void)n_in; (void)out_size; (void)ws_size;
}

// Round 6
// 277.201 us; speedup vs baseline: 2.4742x; 1.0187x over previous
//
#include <hip/hip_runtime.h>
#include <math.h>

#define BB 4
#define NN 2048
#define MM 8192
#define EPSF 1e-5f

typedef _Float16 half8 __attribute__((ext_vector_type(8)));
typedef float f32x4 __attribute__((ext_vector_type(4)));

__device__ __forceinline__ unsigned short f2h(float x) {
    _Float16 h = (_Float16)x;
    return __builtin_bit_cast(unsigned short, h);
}
__device__ __forceinline__ float h2f(unsigned short u) {
    return (float)__builtin_bit_cast(_Float16, u);
}

// ---------------------------------------------------------------------------
// per-batch stats: cc, cn, ncn
// ---------------------------------------------------------------------------
__global__ __launch_bounds__(256) void stats_k(const float* __restrict__ in,
                                               float* __restrict__ st) {
    int b = blockIdx.x;
    int t = threadIdx.x;
    const float* base = in + (size_t)b * 22 * NN;
    float cs0 = 0.f, cs1 = 0.f, cs2 = 0.f, ns0 = 0.f, ns1 = 0.f, ns2 = 0.f;
    for (int n = t; n < NN; n += 256) {
        float cx = base[0 * NN + n], cy = base[1 * NN + n], cz = base[2 * NN + n];
        float nx = base[3 * NN + n], ny = base[4 * NN + n], nz = base[5 * NN + n];
        float inv = 1.0f / sqrtf(nx * nx + ny * ny + nz * nz);
        cs0 += cx; cs1 += cy; cs2 += cz;
        ns0 += nx * inv; ns1 += ny * inv; ns2 += nz * inv;
    }
    __shared__ float red[6][256];
    red[0][t] = cs0; red[1][t] = cs1; red[2][t] = cs2;
    red[3][t] = ns0; red[4][t] = ns1; red[5][t] = ns2;
    __syncthreads();
    for (int s = 128; s > 0; s >>= 1) {
        if (t < s) {
            #pragma unroll
            for (int i = 0; i < 6; ++i) red[i][t] += red[i][t + s];
        }
        __syncthreads();
    }
    if (t == 0) {
        float ccx = red[0][0] / (float)NN, ccy = red[1][0] / (float)NN, ccz = red[2][0] / (float)NN;
        float cnx = red[3][0] / (float)NN, cny = red[4][0] / (float)NN, cnz = red[5][0] / (float)NN;
        float inv = 1.0f / sqrtf(cnx * cnx + cny * cny + cnz * cnz);
        float* s9 = st + b * 16;
        s9[0] = ccx; s9[1] = ccy; s9[2] = ccz;
        s9[3] = cnx; s9[4] = cny; s9[5] = cnz;
        s9[6] = cnx * inv; s9[7] = cny * inv; s9[8] = cnz * inv;
    }
}

__device__ __forceinline__ float angle3(float ux, float uy, float uz,
                                        float vx, float vy, float vz) {
    float crx = uy * vz - uz * vy;
    float cry = uz * vx - ux * vz;
    float crz = ux * vy - uy * vx;
    float s = sqrtf(crx * crx + cry * cry + crz * crz);
    float c = ux * vx + uy * vy + uz * vz;
    return atan2f(s, c);
}

// ---------------------------------------------------------------------------
// per-point PPF (F0 rows 0..3) + packed projected vectors PQ = (x,y,z,|P|)
// ---------------------------------------------------------------------------
__global__ __launch_bounds__(256) void point_k(const float* __restrict__ in,
                                               const float* __restrict__ st,
                                               float4* __restrict__ PQ,
                                               float* __restrict__ F0) {
    int idx = blockIdx.x * 256 + threadIdx.x;
    int b = idx >> 11, n = idx & (NN - 1);
    const float* base = in + (size_t)b * 22 * NN;
    const float* s9 = st + b * 16;
    float cx = base[0 * NN + n], cy = base[1 * NN + n], cz = base[2 * NN + n];
    float nx = base[3 * NN + n], ny = base[4 * NN + n], nz = base[5 * NN + n];
    float inv = 1.0f / sqrtf(nx * nx + ny * ny + nz * nz);
    nx *= inv; ny *= inv; nz *= inv;
    float ccx = s9[0], ccy = s9[1], ccz = s9[2];
    float cnx = s9[3], cny = s9[4], cnz = s9[5];
    float ex = s9[6], ey = s9[7], ez = s9[8];
    float dx = cx - ccx, dy = cy - ccy, dz = cz - ccz;
    F0[0 * MM + idx] = angle3(cnx, cny, cnz, dx, dy, dz);
    F0[1 * MM + idx] = angle3(nx, ny, nz, dx, dy, dz);
    F0[2 * MM + idx] = angle3(cnx, cny, cnz, nx, ny, nz);
    F0[3 * MM + idx] = sqrtf(dx * dx + dy * dy + dz * dz);
    float dot = dx * ex + dy * ey + dz * ez;
    float px = dx - dot * cnx;
    float py = dy - dot * cny;
    float pz = dz - dot * cnz;
    PQ[idx] = make_float4(px, py, pz, sqrtf(px * px + py * py + pz * pz));
}

// ---------------------------------------------------------------------------
// per-row median of pairwise angles. One ROW PER WAVE (max occupancy, no
// LDS). Monotone key = tan^2(theta/2) = ss/(c+|a||b|)^2; key<=2.5e-11 -> +INF
// (matches reference's at<=1e-5 -> 100, sorts last). 20-bit MSB radix select
// via __ballot; value reconstructed once per row as 2*atan(sqrt(key)).
// ---------------------------------------------------------------------------
__global__ __launch_bounds__(256) void alpha_k(const float4* __restrict__ PQ,
                                               float* __restrict__ F0) {
    int row = blockIdx.x * 4 + (threadIdx.x >> 6);
    int lane = threadIdx.x & 63;
    int b = row >> 11;
    const float4* base = PQ + (size_t)b * NN;
    float4 a = base[row & (NN - 1)];
    unsigned u[32];
    #pragma unroll
    for (int s2 = 0; s2 < 32; ++s2) {
        float4 bv = base[s2 * 64 + lane];
        float crx = a.y * bv.z - a.z * bv.y;
        float cry = a.z * bv.x - a.x * bv.z;
        float crz = a.x * bv.y - a.y * bv.x;
        float ss = crx * crx + cry * cry + crz * crz;
        float c = a.x * bv.x + a.y * bv.y + a.z * bv.z;
        float den = c + a.w * bv.w;
        float rc = __builtin_amdgcn_rcpf(den);
        float key = ss * rc * rc;
        if (key <= 2.5e-11f) key = __builtin_inff();
        u[s2] = __float_as_uint(key);
    }
    unsigned p = 0u;
    int k = 1023;
    for (int bit = 30; bit >= 11; --bit) {
        unsigned thr = 1u << bit;
        int cnt = 0;
        #pragma unroll
        for (int s2 = 0; s2 < 32; ++s2)
            cnt += (int)__popcll(__ballot((u[s2] ^ p) < thr));
        if (k >= cnt) { k -= cnt; p |= thr; }
    }
    if (lane == 0)
        F0[4 * MM + row] = 2.0f * atanf(sqrtf(__uint_as_float(p)));
}

// ---------------------------------------------------------------------------
// zero a small region (SUMS + MAXB)
// ---------------------------------------------------------------------------
__global__ void zero_k(float* __restrict__ p) {
    p[blockIdx.x * 256 + threadIdx.x] = 0.f;
}

// ---------------------------------------------------------------------------
// convert all weights to fp16 (K-pad for cls0, O-pad for cls3)
// ---------------------------------------------------------------------------
__global__ __launch_bounds__(256) void wconv_k(const float* __restrict__ w1, const float* __restrict__ w2,
                                               const float* __restrict__ w3, const float* __restrict__ w4,
                                               const float* __restrict__ w5, const float* __restrict__ w6,
                                               const float* __restrict__ w7, unsigned short* __restrict__ Wb) {
    int idx = blockIdx.x * 256 + threadIdx.x;
    unsigned short v;
    if (idx < 8192) v = f2h(w1[idx]);
    else if (idx < 24576) v = f2h(w2[idx - 8192]);
    else if (idx < 155648) v = f2h(w3[idx - 24576]);
    else if (idx < 770048) {
        int l = idx - 155648;
        int o = l / 2400, k = l - o * 2400;
        v = (k < 2384) ? f2h(w4[o * 2384 + k]) : (unsigned short)0;
    } else if (idx < 835584) v = f2h(w5[idx - 770048]);
    else if (idx < 868352) v = f2h(w6[idx - 835584]);
    else {
        int l = idx - 868352;
        int o = l >> 7, k = l & 127;
        v = (o < 50) ? f2h(w7[o * 128 + k]) : (unsigned short)0;
    }
    Wb[idx] = v;
}

// ---------------------------------------------------------------------------
// one-hot rows 0..15 of XCb + zero pad cols 2384..2399
// ---------------------------------------------------------------------------
__global__ __launch_bounds__(256) void onehot_k(const float* __restrict__ in,
                                                unsigned short* __restrict__ XCb) {
    int m = blockIdx.x * 256 + threadIdx.x;
    int b = m >> 11, n = m & (NN - 1);
    const float* src = in + (size_t)b * 22 * NN + 6 * NN + n;
    unsigned short vals[16];
    #pragma unroll
    for (int r = 0; r < 16; ++r) vals[r] = f2h(src[(size_t)r * NN]);
    ushort4* dst = (ushort4*)&XCb[(size_t)m * 2400];
    #pragma unroll
    for (int q = 0; q < 4; ++q)
        dst[q] = make_ushort4(vals[4 * q], vals[4 * q + 1], vals[4 * q + 2], vals[4 * q + 3]);
    ushort4 z = make_ushort4(0, 0, 0, 0);
    ushort4* pz = (ushort4*)&XCb[(size_t)m * 2400 + 2384];
    pz[0] = z; pz[1] = z; pz[2] = z; pz[3] = z;
}

// ---------------------------------------------------------------------------
// pf0: tiny K=5 GEMM, Y (M,64) fp32
// ---------------------------------------------------------------------------
__global__ __launch_bounds__(256) void pf0_k(const float* __restrict__ F0,
                                             const float* __restrict__ W,
                                             float* __restrict__ Y) {
    __shared__ float ws[320];
    int t = threadIdx.x;
    for (int i = t; i < 320; i += 256) ws[i] = W[i];
    __syncthreads();
    int m = blockIdx.x * 256 + t;
    float x0 = F0[m], x1 = F0[MM + m], x2 = F0[2 * MM + m], x3 = F0[3 * MM + m], x4 = F0[4 * MM + m];
    float* ym = Y + (size_t)m * 64;
    #pragma unroll
    for (int o = 0; o < 64; ++o) {
        const float* wo = &ws[o * 5];
        ym[o] = wo[0] * x0 + wo[1] * x1 + wo[2] * x2 + wo[3] * x3 + wo[4] * x4;
    }
}

// ---------------------------------------------------------------------------
// fp16 MFMA GEMM, pipelined: BM=64, BO=128, 4 waves, wave=32x64 (2x4 frags).
// Register-prefetch double-buffer: next K-step's global loads issued before
// the compute barrier so they fly during ds_read+MFMA. Optional K-split via
// blockIdx.z (each chunk writes its own Y partial; doStats must be 0 then).
// ---------------------------------------------------------------------------
__global__ __launch_bounds__(256) void mgemm3_k(const unsigned short* __restrict__ X, int ldx,
                                                const unsigned short* __restrict__ W, int ldw,
                                                float* __restrict__ Y, int Co, int K, int kchunk,
                                                float* __restrict__ sums, int doStats) {
    __shared__ unsigned short As[64 * 32];    // 4KB
    __shared__ unsigned short Bs[128 * 32];   // 8KB
    int t = threadIdx.x;
    int mBase = blockIdx.x * 64;
    int oBase = blockIdx.y * 128;
    int k0c = blockIdx.z * kchunk;
    int k1c = k0c + kchunk; if (k1c > K) k1c = K;
    float* Yp = Y + (size_t)blockIdx.z * MM * Co;
    int lane = t & 63, w = t >> 6;
    int warpM = (w & 1) * 32, warpO = (w >> 1) * 64;
    f32x4 acc[2][4];
    #pragma unroll
    for (int i = 0; i < 2; ++i)
        #pragma unroll
        for (int j = 0; j < 4; ++j) acc[i][j] = (f32x4){0.f, 0.f, 0.f, 0.f};
    int lr = t >> 2;
    int lc = (t & 3) * 8;
    const unsigned short* Xp = X + (size_t)(mBase + lr) * ldx + lc;
    const unsigned short* Wp0 = W + (size_t)(oBase + lr) * ldw + lc;
    const unsigned short* Wp1 = W + (size_t)(oBase + lr + 64) * ldw + lc;
    int ar0 = (warpM + (lane & 15)) * 32 + (lane >> 4) * 8;
    int br0 = (warpO + (lane & 15)) * 32 + (lane >> 4) * 8;
    uint4 xa = *(const uint4*)(Xp + k0c);
    uint4 wb0 = *(const uint4*)(Wp0 + k0c);
    uint4 wb1 = *(const uint4*)(Wp1 + k0c);
    for (int k = k0c; k < k1c; k += 32) {
        __syncthreads();
        *(uint4*)&As[lr * 32 + lc] = xa;
        *(uint4*)&Bs[lr * 32 + lc] = wb0;
        *(uint4*)&Bs[(lr + 64) * 32 + lc] = wb1;
        if (k + 32 < k1c) {
            xa = *(const uint4*)(Xp + k + 32);
            wb0 = *(const uint4*)(Wp0 + k + 32);
            wb1 = *(const uint4*)(Wp1 + k + 32);
        }
        __syncthreads();
        half8 a0 = __builtin_bit_cast(half8, *(const uint4*)&As[ar0]);
        half8 a1 = __builtin_bit_cast(half8, *(const uint4*)&As[ar0 + 16 * 32]);
        half8 b0 = __builtin_bit_cast(half8, *(const uint4*)&Bs[br0]);
        half8 b1 = __builtin_bit_cast(half8, *(const uint4*)&Bs[br0 + 16 * 32]);
        half8 b2 = __builtin_bit_cast(half8, *(const uint4*)&Bs[br0 + 32 * 32]);
        half8 b3 = __builtin_bit_cast(half8, *(const uint4*)&Bs[br0 + 48 * 32]);
        acc[0][0] = __builtin_amdgcn_mfma_f32_16x16x32_f16(a0, b0, acc[0][0], 0, 0, 0);
        acc[0][1] = __builtin_amdgcn_mfma_f32_16x16x32_f16(a0, b1, acc[0][1], 0, 0, 0);
        acc[0][2] = __builtin_amdgcn_mfma_f32_16x16x32_f16(a0, b2, acc[0][2], 0, 0, 0);
        acc[0][3] = __builtin_amdgcn_mfma_f32_16x16x32_f16(a0, b3, acc[0][3], 0, 0, 0);
        acc[1][0] = __builtin_amdgcn_mfma_f32_16x16x32_f16(a1, b0, acc[1][0], 0, 0, 0);
        acc[1][1] = __builtin_amdgcn_mfma_f32_16x16x32_f16(a1, b1, acc[1][1], 0, 0, 0);
        acc[1][2] = __builtin_amdgcn_mfma_f32_16x16x32_f16(a1, b2, acc[1][2], 0, 0, 0);
        acc[1][3] = __builtin_amdgcn_mfma_f32_16x16x32_f16(a1, b3, acc[1][3], 0, 0, 0);
    }
    #pragma unroll
    for (int i = 0; i < 2; ++i) {
        #pragma unroll
        for (int j = 0; j < 4; ++j) {
            int m0 = mBase + warpM + i * 16 + (lane >> 4) * 4;
            int o = oBase + warpO + j * 16 + (lane & 15);
            #pragma unroll
            for (int r = 0; r < 4; ++r)
                Yp[(size_t)(m0 + r) * Co + o] = acc[i][j][r];
        }
    }
    if (doStats) {
        __syncthreads();
        float* ssum = (float*)As;
        float* ssq = (float*)Bs;
        if (t < 128) { ssum[t] = 0.f; ssq[t] = 0.f; }
        __syncthreads();
        #pragma unroll
        for (int j = 0; j < 4; ++j) {
            int oc = warpO + j * 16 + (lane & 15);
            float s = 0.f, q = 0.f;
            #pragma unroll
            for (int i = 0; i < 2; ++i)
                #pragma unroll
                for (int r = 0; r < 4; ++r) { float v = acc[i][j][r]; s += v; q += v * v; }
            atomicAdd(&ssum[oc], s);
            atomicAdd(&ssq[oc], q);
        }
        __syncthreads();
        if (t < 128) {
            atomicAdd(&sums[oBase + t], ssum[t]);
            atomicAdd(&sums[1024 + oBase + t], ssq[t]);
        }
    }
}

// ---------------------------------------------------------------------------
// sum 4 K-split partials into partial 0 (for cls0)
// ---------------------------------------------------------------------------
__global__ __launch_bounds__(256) void reduce4_k(float* __restrict__ Y) {
    int idx4 = blockIdx.x * 256 + threadIdx.x;
    const size_t stride4 = (size_t)MM * 256 / 4;
    float4 v0 = ((const float4*)Y)[idx4];
    float4 v1 = ((const float4*)Y)[idx4 + stride4];
    float4 v2 = ((const float4*)Y)[idx4 + 2 * stride4];
    float4 v3 = ((const float4*)Y)[idx4 + 3 * stride4];
    v0.x += v1.x + v2.x + v3.x;
    v0.y += v1.y + v2.y + v3.y;
    v0.z += v1.z + v2.z + v3.z;
    v0.w += v1.w + v2.w + v3.w;
    ((float4*)Y)[idx4] = v0;
}

// ---------------------------------------------------------------------------
// BN stats from fp32 Y (pf0 Co=64, cls0 Co=256)
// ---------------------------------------------------------------------------
__global__ __launch_bounds__(256) void bnstat_k(const float* __restrict__ Y, int Co,
                                                float* __restrict__ sums) {
    int o0 = blockIdx.x * 64;
    int m0 = blockIdx.y * 512;
    int t = threadIdx.x, ol = t & 63, mg = t >> 6;
    float s = 0.f, q = 0.f;
    const float* p = Y + (size_t)(m0 + mg) * Co + o0 + ol;
    for (int i = 0; i < 128; ++i) {
        float v = p[(size_t)i * 4 * Co];
        s += v; q += v * v;
    }
    __shared__ float ls[4][64], lq[4][64];
    ls[mg][ol] = s; lq[mg][ol] = q;
    __syncthreads();
    if (mg == 0) {
        s = ls[0][ol] + ls[1][ol] + ls[2][ol] + ls[3][ol];
        q = lq[0][ol] + lq[1][ol] + lq[2][ol] + lq[3][ol];
        atomicAdd(&sums[o0 + ol], s);
        atomicAdd(&sums[1024 + o0 + ol], q);
    }
}

// finalize BN coefficients; re-zero consumed sums for next layer
__global__ void bnfin_k(float* __restrict__ sums, const float* __restrict__ g,
                        const float* __restrict__ bb, float* __restrict__ ab, int Co) {
    int o = blockIdx.x * 256 + threadIdx.x;
    if (o >= Co) return;
    float mu = sums[o] * (1.f / 8192.f);
    float var = sums[1024 + o] * (1.f / 8192.f) - mu * mu;
    var = fmaxf(var, 0.f);
    float a = g[o] / sqrtf(var + EPSF);
    ab[2 * o] = a;
    ab[2 * o + 1] = bb[o] - mu * a;
    sums[o] = 0.f;
    sums[1024 + o] = 0.f;
}

// ---------------------------------------------------------------------------
// BN normalize + ReLU + fp16 store into dest slice (ldd-strided)
// ---------------------------------------------------------------------------
__global__ __launch_bounds__(256) void bnorm_k(const float* __restrict__ Y, const float* __restrict__ ab,
                                               unsigned short* __restrict__ dst, int ldd, int shift) {
    int idx4 = blockIdx.x * 256 + threadIdx.x;
    int m = idx4 >> shift;
    int o4 = idx4 & ((1 << shift) - 1);
    float4 v = ((const float4*)Y)[idx4];
    float4 p0 = *(const float4*)&ab[8 * o4];
    float4 p1 = *(const float4*)&ab[8 * o4 + 4];
    ushort4 u;
    u.x = f2h(fmaxf(v.x * p0.x + p0.y, 0.f));
    u.y = f2h(fmaxf(v.y * p0.z + p0.w, 0.f));
    u.z = f2h(fmaxf(v.z * p1.x + p1.y, 0.f));
    u.w = f2h(fmaxf(v.w * p1.z + p1.w, 0.f));
    *(ushort4*)&dst[(size_t)m * ldd + o4 * 4] = u;
}

// ---------------------------------------------------------------------------
// max over N per (b, channel) from pf3's fp16 slice
// ---------------------------------------------------------------------------
__global__ __launch_bounds__(256) void maxred_k(const unsigned short* __restrict__ Xs,
                                                float* __restrict__ maxbuf) {
    int o0 = blockIdx.x * 64;
    int b = blockIdx.y;
    int rc = blockIdx.z;
    int t = threadIdx.x, ol = t & 63, mg = t >> 6;
    float mx = 0.f;
    for (int i = 0; i < 128; ++i) {
        int m = b * NN + rc * 512 + i * 4 + mg;
        mx = fmaxf(mx, h2f(Xs[(size_t)m * 2400 + o0 + ol]));
    }
    __shared__ float ls[4][64];
    ls[mg][ol] = mx;
    __syncthreads();
    if (mg == 0) {
        mx = fmaxf(fmaxf(ls[0][ol], ls[1][ol]), fmaxf(ls[2][ol], ls[3][ol]));
        atomicMax((unsigned*)&maxbuf[b * 1024 + o0 + ol], __builtin_bit_cast(unsigned, mx));
    }
}

__global__ __launch_bounds__(256) void maxbc_k(const float* __restrict__ maxbuf,
                                               unsigned short* __restrict__ XCb) {
    int idx8 = blockIdx.x * 256 + threadIdx.x;
    int m = idx8 >> 7;
    int o8 = (idx8 & 127) * 8;
    int b = m >> 11;
    const float* mb = maxbuf + b * 1024 + o8;
    ushort4 u0 = make_ushort4(f2h(mb[0]), f2h(mb[1]), f2h(mb[2]), f2h(mb[3]));
    ushort4 u1 = make_ushort4(f2h(mb[4]), f2h(mb[5]), f2h(mb[6]), f2h(mb[7]));
    *(ushort4*)&XCb[(size_t)m * 2400 + 1360 + o8] = u0;
    *(ushort4*)&XCb[(size_t)m * 2400 + 1360 + o8 + 4] = u1;
}

// ---------------------------------------------------------------------------
// final: OT(M,128) fp32 -> out (B,50,N) + bias, via LDS transpose
// ---------------------------------------------------------------------------
__global__ __launch_bounds__(256) void wout_k(const float* __restrict__ OT,
                                              const float* __restrict__ bias,
                                              float* __restrict__ out) {
    __shared__ float ts[128][65];
    int t = threadIdx.x;
    int m0 = blockIdx.x * 128;
    #pragma unroll
    for (int i = 0; i < 8; ++i) {
        int idx4 = t + 256 * i;
        int row = idx4 >> 4, c4 = (idx4 & 15) * 4;
        float4 v = *(const float4*)&OT[(size_t)(m0 + row) * 128 + c4];
        ts[row][c4] = v.x; ts[row][c4 + 1] = v.y; ts[row][c4 + 2] = v.z; ts[row][c4 + 3] = v.w;
    }
    __syncthreads();
    int b = m0 >> 11, n0 = m0 & (NN - 1);
    #pragma unroll
    for (int j = 0; j < 25; ++j) {
        int idx = t + 256 * j;
        int o = idx >> 7, nl = idx & 127;
        out[((size_t)b * 50 + o) * NN + n0 + nl] = ts[nl][o] + bias[o];
    }
}

// ---------------------------------------------------------------------------
extern "C" void kernel_launch(void* const* d_in, const int* in_sizes, int n_in,
                              void* d_out, int out_size, void* d_ws, size_t ws_size,
                              hipStream_t stream) {
    const float* in = (const float*)d_in[0];
    const float* pf0_w = (const float*)d_in[1];
    const float* pf_g[4] = {(const float*)d_in[2], (const float*)d_in[5], (const float*)d_in[8], (const float*)d_in[11]};
    const float* pf_b[4] = {(const float*)d_in[3], (const float*)d_in[6], (const float*)d_in[9], (const float*)d_in[12]};
    const float* pf_w[4] = {(const float*)d_in[1], (const float*)d_in[4], (const float*)d_in[7], (const float*)d_in[10]};
    const float* cls_w[3] = {(const float*)d_in[13], (const float*)d_in[16], (const float*)d_in[19]};
    const float* cls_g[3] = {(const float*)d_in[14], (const float*)d_in[17], (const float*)d_in[20]};
    const float* cls_b[3] = {(const float*)d_in[15], (const float*)d_in[18], (const float*)d_in[21]};
    const float* cls3_w = (const float*)d_in[22];
    const float* cls3_bias = (const float*)d_in[23];
    float* out = (float*)d_out;

    char* wsb = (char*)d_ws;
    float* ST = (float*)(wsb + 0);                    // 256 B
    float4* PQ = (float4*)(wsb + 256);                // 131072 B
    float* F0 = (float*)(wsb + 131328);               // 163840 B
    float* SUMS = (float*)(wsb + 295168);             // 8192 B
    float* MAXB = (float*)(wsb + 303360);             // 16384 B
    float* AB = (float*)(wsb + 319744);               // 8192 B
    unsigned short* WB = (unsigned short*)(wsb + 327936);   // 1769472 B
    unsigned short* XCb = (unsigned short*)(wsb + 2097408); // 39321600 B
    unsigned short* C1b = (unsigned short*)(wsb + 41419008); // 4194304 B (reused as C3b)
    unsigned short* C2b = (unsigned short*)(wsb + 45613312); // 4194304 B
    unsigned short* C3b = C1b;                               // C1b dead before cls2's bnorm
    float* Y = (float*)(wsb + 49807616);              // 33554432 B (= 4 cls0 partials)

    zero_k<<<24, 256, 0, stream>>>(SUMS);  // SUMS (2048) + MAXB (4096), contiguous
    wconv_k<<<3456, 256, 0, stream>>>(pf_w[1], pf_w[2], pf_w[3], cls_w[0], cls_w[1], cls_w[2], cls3_w, WB);
    stats_k<<<BB, 256, 0, stream>>>(in, ST);
    point_k<<<MM / 256, 256, 0, stream>>>(in, ST, PQ, F0);
    alpha_k<<<MM / 4, 256, 0, stream>>>(PQ, F0);
    onehot_k<<<MM / 256, 256, 0, stream>>>(in, XCb);

    auto bn = [&](int Co, const float* g, const float* bbias, unsigned short* dst, int ldd, int shift) {
        bnfin_k<<<(Co + 255) / 256, 256, 0, stream>>>(SUMS, g, bbias, AB, Co);
        bnorm_k<<<8 * Co, 256, 0, stream>>>(Y, AB, dst, ldd, shift);
    };

    // pf0 (fp32 path; stats via small bnstat)
    pf0_k<<<MM / 256, 256, 0, stream>>>(F0, pf0_w, Y);
    bnstat_k<<<dim3(1, 16), 256, 0, stream>>>(Y, 64, SUMS);
    bn(64, pf_g[0], pf_b[0], XCb + 16, 2400, 4);
    // pf1 (Co=128, K=64)
    mgemm3_k<<<dim3(128, 1, 1), 256, 0, stream>>>(XCb + 16, 2400, WB, 64, Y, 128, 64, 64, SUMS, 1);
    bn(128, pf_g[1], pf_b[1], XCb + 80, 2400, 5);
    // pf2 (Co=128, K=128)
    mgemm3_k<<<dim3(128, 1, 1), 256, 0, stream>>>(XCb + 80, 2400, WB + 8192, 128, Y, 128, 128, 128, SUMS, 1);
    bn(128, pf_g[2], pf_b[2], XCb + 208, 2400, 5);
    // pf3 (Co=1024, K=128)
    mgemm3_k<<<dim3(128, 8, 1), 256, 0, stream>>>(XCb + 208, 2400, WB + 24576, 128, Y, 1024, 128, 128, SUMS, 1);
    bn(1024, pf_g[3], pf_b[3], XCb + 336, 2400, 8);
    // max feature
    maxred_k<<<dim3(16, 4, 4), 256, 0, stream>>>(XCb + 336, MAXB);
    maxbc_k<<<4096, 256, 0, stream>>>(MAXB, XCb);
    // cls0 (Co=256, K=2400): K-split x4 (chunks of 608=19*32), partials, then reduce
    mgemm3_k<<<dim3(128, 2, 4), 256, 0, stream>>>(XCb, 2400, WB + 155648, 2400, Y, 256, 2400, 608, SUMS, 0);
    reduce4_k<<<2048, 256, 0, stream>>>(Y);
    bnstat_k<<<dim3(4, 16), 256, 0, stream>>>(Y, 256, SUMS);
    bn(256, cls_g[0], cls_b[0], C1b, 256, 6);
    // cls1 (Co=256, K=256)
    mgemm3_k<<<dim3(128, 2, 1), 256, 0, stream>>>(C1b, 256, WB + 770048, 256, Y, 256, 256, 256, SUMS, 1);
    bn(256, cls_g[1], cls_b[1], C2b, 256, 6);
    // cls2 (Co=128, K=256)
    mgemm3_k<<<dim3(128, 1, 1), 256, 0, stream>>>(C2b, 256, WB + 835584, 256, Y, 128, 256, 256, SUMS, 1);
    bn(128, cls_g[2], cls_b[2], C3b, 128, 5);
    // cls3 (padded to 128 outputs, rows 50..127 zero)
    mgemm3_k<<<dim3(128, 1, 1), 256, 0, stream>>>(C3b, 128, WB + 868352, 128, Y, 128, 128, 128, SUMS, 0);
    wout_k<<<MM / 128, 256, 0, stream>>>(Y, cls3_bias, out);

    (void)in_sizes; (void)n_in; (void)out_size; (void)ws_size;
}

// Round 7
// 255.102 us; speedup vs baseline: 2.6885x; 1.0866x over previous
//
#include <hip/hip_runtime.h>
#include <math.h>

#define BB 4
#define NN 2048
#define MM 8192
#define EPSF 1e-5f

typedef _Float16 half8 __attribute__((ext_vector_type(8)));
typedef float f32x4 __attribute__((ext_vector_type(4)));

__device__ __forceinline__ unsigned short f2h(float x) {
    _Float16 h = (_Float16)x;
    return __builtin_bit_cast(unsigned short, h);
}
__device__ __forceinline__ float h2f(unsigned short u) {
    return (float)__builtin_bit_cast(_Float16, u);
}

// ---------------------------------------------------------------------------
// per-batch stats: cc, cn, ncn
// ---------------------------------------------------------------------------
__global__ __launch_bounds__(256) void stats_k(const float* __restrict__ in,
                                               float* __restrict__ st) {
    int b = blockIdx.x;
    int t = threadIdx.x;
    const float* base = in + (size_t)b * 22 * NN;
    float cs0 = 0.f, cs1 = 0.f, cs2 = 0.f, ns0 = 0.f, ns1 = 0.f, ns2 = 0.f;
    for (int n = t; n < NN; n += 256) {
        float cx = base[0 * NN + n], cy = base[1 * NN + n], cz = base[2 * NN + n];
        float nx = base[3 * NN + n], ny = base[4 * NN + n], nz = base[5 * NN + n];
        float inv = 1.0f / sqrtf(nx * nx + ny * ny + nz * nz);
        cs0 += cx; cs1 += cy; cs2 += cz;
        ns0 += nx * inv; ns1 += ny * inv; ns2 += nz * inv;
    }
    __shared__ float red[6][256];
    red[0][t] = cs0; red[1][t] = cs1; red[2][t] = cs2;
    red[3][t] = ns0; red[4][t] = ns1; red[5][t] = ns2;
    __syncthreads();
    for (int s = 128; s > 0; s >>= 1) {
        if (t < s) {
            #pragma unroll
            for (int i = 0; i < 6; ++i) red[i][t] += red[i][t + s];
        }
        __syncthreads();
    }
    if (t == 0) {
        float ccx = red[0][0] / (float)NN, ccy = red[1][0] / (float)NN, ccz = red[2][0] / (float)NN;
        float cnx = red[3][0] / (float)NN, cny = red[4][0] / (float)NN, cnz = red[5][0] / (float)NN;
        float inv = 1.0f / sqrtf(cnx * cnx + cny * cny + cnz * cnz);
        float* s9 = st + b * 16;
        s9[0] = ccx; s9[1] = ccy; s9[2] = ccz;
        s9[3] = cnx; s9[4] = cny; s9[5] = cnz;
        s9[6] = cnx * inv; s9[7] = cny * inv; s9[8] = cnz * inv;
    }
}

__device__ __forceinline__ float angle3(float ux, float uy, float uz,
                                        float vx, float vy, float vz) {
    float crx = uy * vz - uz * vy;
    float cry = uz * vx - ux * vz;
    float crz = ux * vy - uy * vx;
    float s = sqrtf(crx * crx + cry * cry + crz * crz);
    float c = ux * vx + uy * vy + uz * vz;
    return atan2f(s, c);
}

// ---------------------------------------------------------------------------
// per-point PPF (F0 rows 0..3) + packed projected vectors PQ = (x,y,z,|P|)
// ---------------------------------------------------------------------------
__global__ __launch_bounds__(256) void point_k(const float* __restrict__ in,
                                               const float* __restrict__ st,
                                               float4* __restrict__ PQ,
                                               float* __restrict__ F0) {
    int idx = blockIdx.x * 256 + threadIdx.x;
    int b = idx >> 11, n = idx & (NN - 1);
    const float* base = in + (size_t)b * 22 * NN;
    const float* s9 = st + b * 16;
    float cx = base[0 * NN + n], cy = base[1 * NN + n], cz = base[2 * NN + n];
    float nx = base[3 * NN + n], ny = base[4 * NN + n], nz = base[5 * NN + n];
    float inv = 1.0f / sqrtf(nx * nx + ny * ny + nz * nz);
    nx *= inv; ny *= inv; nz *= inv;
    float ccx = s9[0], ccy = s9[1], ccz = s9[2];
    float cnx = s9[3], cny = s9[4], cnz = s9[5];
    float ex = s9[6], ey = s9[7], ez = s9[8];
    float dx = cx - ccx, dy = cy - ccy, dz = cz - ccz;
    F0[0 * MM + idx] = angle3(cnx, cny, cnz, dx, dy, dz);
    F0[1 * MM + idx] = angle3(nx, ny, nz, dx, dy, dz);
    F0[2 * MM + idx] = angle3(cnx, cny, cnz, nx, ny, nz);
    F0[3 * MM + idx] = sqrtf(dx * dx + dy * dy + dz * dz);
    float dot = dx * ex + dy * ey + dz * ez;
    float px = dx - dot * cnx;
    float py = dy - dot * cny;
    float pz = dz - dot * cnz;
    PQ[idx] = make_float4(px, py, pz, sqrtf(px * px + py * py + pz * pz));
}

// ---------------------------------------------------------------------------
// per-row median of pairwise angles. TWO rows per wave (shared column loads,
// interleaved independent count chains for ILP). Monotone key = tan^2(th/2);
// key<=2.5e-11 -> +INF (matches reference at<=1e-5 -> 100). Greedy 20-bit
// search for largest T with #{u < T} <= 1023 (1 v_cmp per value per bit).
// Value reconstructed once per row as 2*atan(sqrt(T)).
// ---------------------------------------------------------------------------
__global__ __launch_bounds__(256) void alpha_k(const float4* __restrict__ PQ,
                                               float* __restrict__ F0) {
    int wid = blockIdx.x * 4 + (threadIdx.x >> 6);
    int lane = threadIdx.x & 63;
    int r0 = wid * 2;                 // rows r0, r0+1 (same batch)
    int b = r0 >> 11;
    int rl = r0 & (NN - 1);
    const float4* base = PQ + (size_t)b * NN;
    float4 a0 = base[rl];
    float4 a1 = base[rl + 1];
    unsigned u0[32], u1[32];
    #pragma unroll 4
    for (int s2 = 0; s2 < 32; ++s2) {
        float4 bv = base[s2 * 64 + lane];
        {
            float cx = a0.y * bv.z - a0.z * bv.y;
            float cy = a0.z * bv.x - a0.x * bv.z;
            float cz = a0.x * bv.y - a0.y * bv.x;
            float ss = cx * cx + cy * cy + cz * cz;
            float dc = a0.x * bv.x + a0.y * bv.y + a0.z * bv.z;
            float den = dc + a0.w * bv.w;
            float rc = __builtin_amdgcn_rcpf(den);
            float key = ss * rc * rc;
            u0[s2] = (key <= 2.5e-11f) ? 0x7F800000u : __float_as_uint(key);
        }
        {
            float cx = a1.y * bv.z - a1.z * bv.y;
            float cy = a1.z * bv.x - a1.x * bv.z;
            float cz = a1.x * bv.y - a1.y * bv.x;
            float ss = cx * cx + cy * cy + cz * cz;
            float dc = a1.x * bv.x + a1.y * bv.y + a1.z * bv.z;
            float den = dc + a1.w * bv.w;
            float rc = __builtin_amdgcn_rcpf(den);
            float key = ss * rc * rc;
            u1[s2] = (key <= 2.5e-11f) ? 0x7F800000u : __float_as_uint(key);
        }
    }
    unsigned T0 = 0u, T1 = 0u;
    for (int bit = 30; bit >= 11; --bit) {
        unsigned c0 = T0 | (1u << bit);
        unsigned c1 = T1 | (1u << bit);
        int n0 = 0, n1 = 0;
        #pragma unroll
        for (int s2 = 0; s2 < 32; ++s2) {
            n0 += (int)__popcll(__ballot(u0[s2] < c0));
            n1 += (int)__popcll(__ballot(u1[s2] < c1));
        }
        if (n0 <= 1023) T0 = c0;
        if (n1 <= 1023) T1 = c1;
    }
    if (lane == 0) {
        F0[4 * MM + b * NN + rl] = 2.0f * atanf(sqrtf(__uint_as_float(T0)));
        F0[4 * MM + b * NN + rl + 1] = 2.0f * atanf(sqrtf(__uint_as_float(T1)));
    }
}

// ---------------------------------------------------------------------------
// zero a small region (all SUMS slices + MAXB, contiguous)
// ---------------------------------------------------------------------------
__global__ void zero_k(float* __restrict__ p) {
    p[blockIdx.x * 256 + threadIdx.x] = 0.f;
}

// ---------------------------------------------------------------------------
// convert all weights to fp16 (K-pad for cls0, O-pad for cls3)
// ---------------------------------------------------------------------------
__global__ __launch_bounds__(256) void wconv_k(const float* __restrict__ w1, const float* __restrict__ w2,
                                               const float* __restrict__ w3, const float* __restrict__ w4,
                                               const float* __restrict__ w5, const float* __restrict__ w6,
                                               const float* __restrict__ w7, unsigned short* __restrict__ Wb) {
    int idx = blockIdx.x * 256 + threadIdx.x;
    unsigned short v;
    if (idx < 8192) v = f2h(w1[idx]);
    else if (idx < 24576) v = f2h(w2[idx - 8192]);
    else if (idx < 155648) v = f2h(w3[idx - 24576]);
    else if (idx < 770048) {
        int l = idx - 155648;
        int o = l / 2400, k = l - o * 2400;
        v = (k < 2384) ? f2h(w4[o * 2384 + k]) : (unsigned short)0;
    } else if (idx < 835584) v = f2h(w5[idx - 770048]);
    else if (idx < 868352) v = f2h(w6[idx - 835584]);
    else {
        int l = idx - 868352;
        int o = l >> 7, k = l & 127;
        v = (o < 50) ? f2h(w7[o * 128 + k]) : (unsigned short)0;
    }
    Wb[idx] = v;
}

// ---------------------------------------------------------------------------
// one-hot rows 0..15 of XCb + zero pad cols 2384..2399
// ---------------------------------------------------------------------------
__global__ __launch_bounds__(256) void onehot_k(const float* __restrict__ in,
                                                unsigned short* __restrict__ XCb) {
    int m = blockIdx.x * 256 + threadIdx.x;
    int b = m >> 11, n = m & (NN - 1);
    const float* src = in + (size_t)b * 22 * NN + 6 * NN + n;
    unsigned short vals[16];
    #pragma unroll
    for (int r = 0; r < 16; ++r) vals[r] = f2h(src[(size_t)r * NN]);
    ushort4* dst = (ushort4*)&XCb[(size_t)m * 2400];
    #pragma unroll
    for (int q = 0; q < 4; ++q)
        dst[q] = make_ushort4(vals[4 * q], vals[4 * q + 1], vals[4 * q + 2], vals[4 * q + 3]);
    ushort4 z = make_ushort4(0, 0, 0, 0);
    ushort4* pz = (ushort4*)&XCb[(size_t)m * 2400 + 2384];
    pz[0] = z; pz[1] = z; pz[2] = z; pz[3] = z;
}

// ---------------------------------------------------------------------------
// pf0: tiny K=5 GEMM, Y (M,64) fp32
// ---------------------------------------------------------------------------
__global__ __launch_bounds__(256) void pf0_k(const float* __restrict__ F0,
                                             const float* __restrict__ W,
                                             float* __restrict__ Y) {
    __shared__ float ws[320];
    int t = threadIdx.x;
    for (int i = t; i < 320; i += 256) ws[i] = W[i];
    __syncthreads();
    int m = blockIdx.x * 256 + t;
    float x0 = F0[m], x1 = F0[MM + m], x2 = F0[2 * MM + m], x3 = F0[3 * MM + m], x4 = F0[4 * MM + m];
    float* ym = Y + (size_t)m * 64;
    #pragma unroll
    for (int o = 0; o < 64; ++o) {
        const float* wo = &ws[o * 5];
        ym[o] = wo[0] * x0 + wo[1] * x1 + wo[2] * x2 + wo[3] * x3 + wo[4] * x4;
    }
}

// ---------------------------------------------------------------------------
// fp16 MFMA GEMM, pipelined: BM=64, BO=128, 4 waves, wave=32x64.
// MODE 0: fp32 Y write, no stats (supports K-split via blockIdx.z).
// MODE 1: fp16 Y write + fused BN-stat epilogue into sums slice.
// ---------------------------------------------------------------------------
template<int MODE>
__global__ __launch_bounds__(256) void mgemm3_k(const unsigned short* __restrict__ X, int ldx,
                                                const unsigned short* __restrict__ W, int ldw,
                                                void* __restrict__ Yv, int Co, int K, int kchunk,
                                                float* __restrict__ sums) {
    __shared__ unsigned short As[64 * 32];    // 4KB
    __shared__ unsigned short Bs[128 * 32];   // 8KB
    int t = threadIdx.x;
    int mBase = blockIdx.x * 64;
    int oBase = blockIdx.y * 128;
    int k0c = blockIdx.z * kchunk;
    int k1c = k0c + kchunk; if (k1c > K) k1c = K;
    int lane = t & 63, w = t >> 6;
    int warpM = (w & 1) * 32, warpO = (w >> 1) * 64;
    f32x4 acc[2][4];
    #pragma unroll
    for (int i = 0; i < 2; ++i)
        #pragma unroll
        for (int j = 0; j < 4; ++j) acc[i][j] = (f32x4){0.f, 0.f, 0.f, 0.f};
    int lr = t >> 2;
    int lc = (t & 3) * 8;
    const unsigned short* Xp = X + (size_t)(mBase + lr) * ldx + lc;
    const unsigned short* Wp0 = W + (size_t)(oBase + lr) * ldw + lc;
    const unsigned short* Wp1 = W + (size_t)(oBase + lr + 64) * ldw + lc;
    int ar0 = (warpM + (lane & 15)) * 32 + (lane >> 4) * 8;
    int br0 = (warpO + (lane & 15)) * 32 + (lane >> 4) * 8;
    uint4 xa = *(const uint4*)(Xp + k0c);
    uint4 wb0 = *(const uint4*)(Wp0 + k0c);
    uint4 wb1 = *(const uint4*)(Wp1 + k0c);
    for (int k = k0c; k < k1c; k += 32) {
        __syncthreads();
        *(uint4*)&As[lr * 32 + lc] = xa;
        *(uint4*)&Bs[lr * 32 + lc] = wb0;
        *(uint4*)&Bs[(lr + 64) * 32 + lc] = wb1;
        if (k + 32 < k1c) {
            xa = *(const uint4*)(Xp + k + 32);
            wb0 = *(const uint4*)(Wp0 + k + 32);
            wb1 = *(const uint4*)(Wp1 + k + 32);
        }
        __syncthreads();
        half8 a0 = __builtin_bit_cast(half8, *(const uint4*)&As[ar0]);
        half8 a1 = __builtin_bit_cast(half8, *(const uint4*)&As[ar0 + 16 * 32]);
        half8 b0 = __builtin_bit_cast(half8, *(const uint4*)&Bs[br0]);
        half8 b1 = __builtin_bit_cast(half8, *(const uint4*)&Bs[br0 + 16 * 32]);
        half8 b2 = __builtin_bit_cast(half8, *(const uint4*)&Bs[br0 + 32 * 32]);
        half8 b3 = __builtin_bit_cast(half8, *(const uint4*)&Bs[br0 + 48 * 32]);
        acc[0][0] = __builtin_amdgcn_mfma_f32_16x16x32_f16(a0, b0, acc[0][0], 0, 0, 0);
        acc[0][1] = __builtin_amdgcn_mfma_f32_16x16x32_f16(a0, b1, acc[0][1], 0, 0, 0);
        acc[0][2] = __builtin_amdgcn_mfma_f32_16x16x32_f16(a0, b2, acc[0][2], 0, 0, 0);
        acc[0][3] = __builtin_amdgcn_mfma_f32_16x16x32_f16(a0, b3, acc[0][3], 0, 0, 0);
        acc[1][0] = __builtin_amdgcn_mfma_f32_16x16x32_f16(a1, b0, acc[1][0], 0, 0, 0);
        acc[1][1] = __builtin_amdgcn_mfma_f32_16x16x32_f16(a1, b1, acc[1][1], 0, 0, 0);
        acc[1][2] = __builtin_amdgcn_mfma_f32_16x16x32_f16(a1, b2, acc[1][2], 0, 0, 0);
        acc[1][3] = __builtin_amdgcn_mfma_f32_16x16x32_f16(a1, b3, acc[1][3], 0, 0, 0);
    }
    if (MODE == 0) {
        float* Yp = (float*)Yv + (size_t)blockIdx.z * MM * Co;
        #pragma unroll
        for (int i = 0; i < 2; ++i)
            #pragma unroll
            for (int j = 0; j < 4; ++j) {
                int m0 = mBase + warpM + i * 16 + (lane >> 4) * 4;
                int o = oBase + warpO + j * 16 + (lane & 15);
                #pragma unroll
                for (int r = 0; r < 4; ++r)
                    Yp[(size_t)(m0 + r) * Co + o] = acc[i][j][r];
            }
    } else {
        unsigned short* Yh = (unsigned short*)Yv;
        #pragma unroll
        for (int i = 0; i < 2; ++i)
            #pragma unroll
            for (int j = 0; j < 4; ++j) {
                int m0 = mBase + warpM + i * 16 + (lane >> 4) * 4;
                int o = oBase + warpO + j * 16 + (lane & 15);
                #pragma unroll
                for (int r = 0; r < 4; ++r)
                    Yh[(size_t)(m0 + r) * Co + o] = f2h(acc[i][j][r]);
            }
        __syncthreads();
        float* ssum = (float*)As;
        float* ssq = (float*)Bs;
        if (t < 128) { ssum[t] = 0.f; ssq[t] = 0.f; }
        __syncthreads();
        #pragma unroll
        for (int j = 0; j < 4; ++j) {
            int oc = warpO + j * 16 + (lane & 15);
            float s = 0.f, q = 0.f;
            #pragma unroll
            for (int i = 0; i < 2; ++i)
                #pragma unroll
                for (int r = 0; r < 4; ++r) { float v = acc[i][j][r]; s += v; q += v * v; }
            atomicAdd(&ssum[oc], s);
            atomicAdd(&ssq[oc], q);
        }
        __syncthreads();
        if (t < 128) {
            atomicAdd(&sums[oBase + t], ssum[t]);
            atomicAdd(&sums[1024 + oBase + t], ssq[t]);
        }
    }
}

// ---------------------------------------------------------------------------
// sum 4 K-split partials into partial 0 (for cls0)
// ---------------------------------------------------------------------------
__global__ __launch_bounds__(256) void reduce4_k(float* __restrict__ Y) {
    int idx4 = blockIdx.x * 256 + threadIdx.x;
    const size_t stride4 = (size_t)MM * 256 / 4;
    float4 v0 = ((const float4*)Y)[idx4];
    float4 v1 = ((const float4*)Y)[idx4 + stride4];
    float4 v2 = ((const float4*)Y)[idx4 + 2 * stride4];
    float4 v3 = ((const float4*)Y)[idx4 + 3 * stride4];
    v0.x += v1.x + v2.x + v3.x;
    v0.y += v1.y + v2.y + v3.y;
    v0.z += v1.z + v2.z + v3.z;
    v0.w += v1.w + v2.w + v3.w;
    ((float4*)Y)[idx4] = v0;
}

// ---------------------------------------------------------------------------
// BN stats from fp32 Y (pf0, cls0) into a sums slice
// ---------------------------------------------------------------------------
__global__ __launch_bounds__(256) void bnstat_k(const float* __restrict__ Y, int Co,
                                                float* __restrict__ sums) {
    int o0 = blockIdx.x * 64;
    int m0 = blockIdx.y * 512;
    int t = threadIdx.x, ol = t & 63, mg = t >> 6;
    float s = 0.f, q = 0.f;
    const float* p = Y + (size_t)(m0 + mg) * Co + o0 + ol;
    for (int i = 0; i < 128; ++i) {
        float v = p[(size_t)i * 4 * Co];
        s += v; q += v * v;
    }
    __shared__ float ls[4][64], lq[4][64];
    ls[mg][ol] = s; lq[mg][ol] = q;
    __syncthreads();
    if (mg == 0) {
        s = ls[0][ol] + ls[1][ol] + ls[2][ol] + ls[3][ol];
        q = lq[0][ol] + lq[1][ol] + lq[2][ol] + lq[3][ol];
        atomicAdd(&sums[o0 + ol], s);
        atomicAdd(&sums[1024 + o0 + ol], q);
    }
}

// inline BN coefficient from sums slice
__device__ __forceinline__ void bncoef(const float* __restrict__ sums,
                                       const float* __restrict__ g,
                                       const float* __restrict__ bb,
                                       int o, float& a, float& c) {
    float mu = sums[o] * (1.f / 8192.f);
    float var = sums[1024 + o] * (1.f / 8192.f) - mu * mu;
    var = fmaxf(var, 0.f);
    a = g[o] * (1.0f / sqrtf(var + EPSF));
    c = bb[o] - mu * a;
}

// ---------------------------------------------------------------------------
// BN normalize + ReLU + fp16 store (fp32 source)
// ---------------------------------------------------------------------------
__global__ __launch_bounds__(256) void bnorm_f(const float* __restrict__ Y,
                                               const float* __restrict__ sums,
                                               const float* __restrict__ g,
                                               const float* __restrict__ bb,
                                               unsigned short* __restrict__ dst, int ldd, int shift) {
    int idx4 = blockIdx.x * 256 + threadIdx.x;
    int m = idx4 >> shift;
    int o4 = (idx4 & ((1 << shift) - 1)) * 4;
    float4 v = ((const float4*)Y)[idx4];
    float vv[4] = {v.x, v.y, v.z, v.w};
    unsigned short r[4];
    #pragma unroll
    for (int j = 0; j < 4; ++j) {
        float a, c;
        bncoef(sums, g, bb, o4 + j, a, c);
        r[j] = f2h(fmaxf(vv[j] * a + c, 0.f));
    }
    *(ushort4*)&dst[(size_t)m * ldd + o4] = make_ushort4(r[0], r[1], r[2], r[3]);
}

// ---------------------------------------------------------------------------
// BN normalize + ReLU + fp16 store (fp16 source)
// ---------------------------------------------------------------------------
__global__ __launch_bounds__(256) void bnorm_h(const unsigned short* __restrict__ Yh,
                                               const float* __restrict__ sums,
                                               const float* __restrict__ g,
                                               const float* __restrict__ bb,
                                               unsigned short* __restrict__ dst, int ldd, int shift) {
    int idx4 = blockIdx.x * 256 + threadIdx.x;
    int m = idx4 >> shift;
    int o4 = (idx4 & ((1 << shift) - 1)) * 4;
    ushort4 hv = ((const ushort4*)Yh)[idx4];
    float vv[4] = {h2f(hv.x), h2f(hv.y), h2f(hv.z), h2f(hv.w)};
    unsigned short r[4];
    #pragma unroll
    for (int j = 0; j < 4; ++j) {
        float a, c;
        bncoef(sums, g, bb, o4 + j, a, c);
        r[j] = f2h(fmaxf(vv[j] * a + c, 0.f));
    }
    *(ushort4*)&dst[(size_t)m * ldd + o4] = make_ushort4(r[0], r[1], r[2], r[3]);
}

// ---------------------------------------------------------------------------
// max over N per (b, channel) from pf3's fp16 slice
// ---------------------------------------------------------------------------
__global__ __launch_bounds__(256) void maxred_k(const unsigned short* __restrict__ Xs,
                                                float* __restrict__ maxbuf) {
    int o0 = blockIdx.x * 64;
    int b = blockIdx.y;
    int rc = blockIdx.z;
    int t = threadIdx.x, ol = t & 63, mg = t >> 6;
    float mx = 0.f;
    for (int i = 0; i < 128; ++i) {
        int m = b * NN + rc * 512 + i * 4 + mg;
        mx = fmaxf(mx, h2f(Xs[(size_t)m * 2400 + o0 + ol]));
    }
    __shared__ float ls[4][64];
    ls[mg][ol] = mx;
    __syncthreads();
    if (mg == 0) {
        mx = fmaxf(fmaxf(ls[0][ol], ls[1][ol]), fmaxf(ls[2][ol], ls[3][ol]));
        atomicMax((unsigned*)&maxbuf[b * 1024 + o0 + ol], __builtin_bit_cast(unsigned, mx));
    }
}

__global__ __launch_bounds__(256) void maxbc_k(const float* __restrict__ maxbuf,
                                               unsigned short* __restrict__ XCb) {
    int idx8 = blockIdx.x * 256 + threadIdx.x;
    int m = idx8 >> 7;
    int o8 = (idx8 & 127) * 8;
    int b = m >> 11;
    const float* mb = maxbuf + b * 1024 + o8;
    ushort4 u0 = make_ushort4(f2h(mb[0]), f2h(mb[1]), f2h(mb[2]), f2h(mb[3]));
    ushort4 u1 = make_ushort4(f2h(mb[4]), f2h(mb[5]), f2h(mb[6]), f2h(mb[7]));
    *(ushort4*)&XCb[(size_t)m * 2400 + 1360 + o8] = u0;
    *(ushort4*)&XCb[(size_t)m * 2400 + 1360 + o8 + 4] = u1;
}

// ---------------------------------------------------------------------------
// final: OT(M,128) fp32 -> out (B,50,N) + bias, via LDS transpose
// ---------------------------------------------------------------------------
__global__ __launch_bounds__(256) void wout_k(const float* __restrict__ OT,
                                              const float* __restrict__ bias,
                                              float* __restrict__ out) {
    __shared__ float ts[128][65];
    int t = threadIdx.x;
    int m0 = blockIdx.x * 128;
    #pragma unroll
    for (int i = 0; i < 8; ++i) {
        int idx4 = t + 256 * i;
        int row = idx4 >> 4, c4 = (idx4 & 15) * 4;
        float4 v = *(const float4*)&OT[(size_t)(m0 + row) * 128 + c4];
        ts[row][c4] = v.x; ts[row][c4 + 1] = v.y; ts[row][c4 + 2] = v.z; ts[row][c4 + 3] = v.w;
    }
    __syncthreads();
    int b = m0 >> 11, n0 = m0 & (NN - 1);
    #pragma unroll
    for (int j = 0; j < 25; ++j) {
        int idx = t + 256 * j;
        int o = idx >> 7, nl = idx & 127;
        out[((size_t)b * 50 + o) * NN + n0 + nl] = ts[nl][o] + bias[o];
    }
}

// ---------------------------------------------------------------------------
extern "C" void kernel_launch(void* const* d_in, const int* in_sizes, int n_in,
                              void* d_out, int out_size, void* d_ws, size_t ws_size,
                              hipStream_t stream) {
    const float* in = (const float*)d_in[0];
    const float* pf0_w = (const float*)d_in[1];
    const float* pf_g[4] = {(const float*)d_in[2], (const float*)d_in[5], (const float*)d_in[8], (const float*)d_in[11]};
    const float* pf_b[4] = {(const float*)d_in[3], (const float*)d_in[6], (const float*)d_in[9], (const float*)d_in[12]};
    const float* pf_w[4] = {(const float*)d_in[1], (const float*)d_in[4], (const float*)d_in[7], (const float*)d_in[10]};
    const float* cls_w[3] = {(const float*)d_in[13], (const float*)d_in[16], (const float*)d_in[19]};
    const float* cls_g[3] = {(const float*)d_in[14], (const float*)d_in[17], (const float*)d_in[20]};
    const float* cls_b[3] = {(const float*)d_in[15], (const float*)d_in[18], (const float*)d_in[21]};
    const float* cls3_w = (const float*)d_in[22];
    const float* cls3_bias = (const float*)d_in[23];
    float* out = (float*)d_out;

    char* wsb = (char*)d_ws;
    float* ST = (float*)(wsb + 0);                      // 256 B
    float4* PQ = (float4*)(wsb + 256);                  // 131072 B
    float* F0 = (float*)(wsb + 131328);                 // 163840 B
    float* SUMS = (float*)(wsb + 295168);               // 7 slices x 8192 B = 57344 B
    float* MAXB = (float*)(wsb + 352512);               // 16384 B (right after SUMS)
    unsigned short* WB = (unsigned short*)(wsb + 368896);    // 1769472 B
    unsigned short* XCb = (unsigned short*)(wsb + 2138368);  // 39321600 B
    unsigned short* C1b = (unsigned short*)(wsb + 41459968); // 4194304 B (aliased as C3b)
    unsigned short* C2b = (unsigned short*)(wsb + 45654272); // 4194304 B
    unsigned short* C3b = C1b;
    float* Y = (float*)(wsb + 49848576);                // 33554432 B (4 cls0 partials)
    unsigned short* Yh = (unsigned short*)Y;

    auto SL = [&](int s) { return SUMS + (size_t)s * 2048; };

    zero_k<<<72, 256, 0, stream>>>(SUMS);  // 7 SUMS slices + MAXB (contiguous)
    wconv_k<<<3456, 256, 0, stream>>>(pf_w[1], pf_w[2], pf_w[3], cls_w[0], cls_w[1], cls_w[2], cls3_w, WB);
    stats_k<<<BB, 256, 0, stream>>>(in, ST);
    point_k<<<MM / 256, 256, 0, stream>>>(in, ST, PQ, F0);
    alpha_k<<<MM / 8, 256, 0, stream>>>(PQ, F0);
    onehot_k<<<MM / 256, 256, 0, stream>>>(in, XCb);

    // pf0 (fp32 path)
    pf0_k<<<MM / 256, 256, 0, stream>>>(F0, pf0_w, Y);
    bnstat_k<<<dim3(1, 16), 256, 0, stream>>>(Y, 64, SL(0));
    bnorm_f<<<512, 256, 0, stream>>>(Y, SL(0), pf_g[0], pf_b[0], XCb + 16, 2400, 4);
    // pf1 (Co=128, K=64)
    mgemm3_k<1><<<dim3(128, 1, 1), 256, 0, stream>>>(XCb + 16, 2400, WB, 64, Yh, 128, 64, 64, SL(1));
    bnorm_h<<<1024, 256, 0, stream>>>(Yh, SL(1), pf_g[1], pf_b[1], XCb + 80, 2400, 5);
    // pf2 (Co=128, K=128)
    mgemm3_k<1><<<dim3(128, 1, 1), 256, 0, stream>>>(XCb + 80, 2400, WB + 8192, 128, Yh, 128, 128, 128, SL(2));
    bnorm_h<<<1024, 256, 0, stream>>>(Yh, SL(2), pf_g[2], pf_b[2], XCb + 208, 2400, 5);
    // pf3 (Co=1024, K=128)
    mgemm3_k<1><<<dim3(128, 8, 1), 256, 0, stream>>>(XCb + 208, 2400, WB + 24576, 128, Yh, 1024, 128, 128, SL(3));
    bnorm_h<<<8192, 256, 0, stream>>>(Yh, SL(3), pf_g[3], pf_b[3], XCb + 336, 2400, 8);
    // max feature
    maxred_k<<<dim3(16, 4, 4), 256, 0, stream>>>(XCb + 336, MAXB);
    maxbc_k<<<4096, 256, 0, stream>>>(MAXB, XCb);
    // cls0 (Co=256, K=2400): K-split x4, fp32 partials, reduce, stats, norm
    mgemm3_k<0><<<dim3(128, 2, 4), 256, 0, stream>>>(XCb, 2400, WB + 155648, 2400, Y, 256, 2400, 608, SL(4));
    reduce4_k<<<2048, 256, 0, stream>>>(Y);
    bnstat_k<<<dim3(4, 16), 256, 0, stream>>>(Y, 256, SL(4));
    bnorm_f<<<2048, 256, 0, stream>>>(Y, SL(4), cls_g[0], cls_b[0], C1b, 256, 6);
    // cls1 (Co=256, K=256)
    mgemm3_k<1><<<dim3(128, 2, 1), 256, 0, stream>>>(C1b, 256, WB + 770048, 256, Yh, 256, 256, 256, SL(5));
    bnorm_h<<<2048, 256, 0, stream>>>(Yh, SL(5), cls_g[1], cls_b[1], C2b, 256, 6);
    // cls2 (Co=128, K=256)
    mgemm3_k<1><<<dim3(128, 1, 1), 256, 0, stream>>>(C2b, 256, WB + 835584, 256, Yh, 128, 256, 256, SL(6));
    bnorm_h<<<1024, 256, 0, stream>>>(Yh, SL(6), cls_g[2], cls_b[2], C3b, 128, 5);
    // cls3 (padded to 128 outputs, rows 50..127 zero) -> fp32 Y
    mgemm3_k<0><<<dim3(128, 1, 1), 256, 0, stream>>>(C3b, 128, WB + 868352, 128, Y, 128, 128, 128, SL(0));
    wout_k<<<MM / 128, 256, 0, stream>>>(Y, cls3_bias, out);

    (void)in_sizes; (void)n_in; (void)out_size; (void)ws_size;
}

// Round 8
// 248.303 us; speedup vs baseline: 2.7621x; 1.0274x over previous
//
#include <hip/hip_runtime.h>
#include <math.h>

#define BB 4
#define NN 2048
#define MM 8192
#define EPSF 1e-5f

typedef _Float16 half8 __attribute__((ext_vector_type(8)));
typedef float f32x4 __attribute__((ext_vector_type(4)));

__device__ __forceinline__ unsigned short f2h(float x) {
    _Float16 h = (_Float16)x;
    return __builtin_bit_cast(unsigned short, h);
}
__device__ __forceinline__ float h2f(unsigned short u) {
    return (float)__builtin_bit_cast(_Float16, u);
}

// ---------------------------------------------------------------------------
// per-batch stats: cc, cn, ncn
// ---------------------------------------------------------------------------
__global__ __launch_bounds__(256) void stats_k(const float* __restrict__ in,
                                               float* __restrict__ st) {
    int b = blockIdx.x;
    int t = threadIdx.x;
    const float* base = in + (size_t)b * 22 * NN;
    float cs0 = 0.f, cs1 = 0.f, cs2 = 0.f, ns0 = 0.f, ns1 = 0.f, ns2 = 0.f;
    for (int n = t; n < NN; n += 256) {
        float cx = base[0 * NN + n], cy = base[1 * NN + n], cz = base[2 * NN + n];
        float nx = base[3 * NN + n], ny = base[4 * NN + n], nz = base[5 * NN + n];
        float inv = 1.0f / sqrtf(nx * nx + ny * ny + nz * nz);
        cs0 += cx; cs1 += cy; cs2 += cz;
        ns0 += nx * inv; ns1 += ny * inv; ns2 += nz * inv;
    }
    __shared__ float red[6][256];
    red[0][t] = cs0; red[1][t] = cs1; red[2][t] = cs2;
    red[3][t] = ns0; red[4][t] = ns1; red[5][t] = ns2;
    __syncthreads();
    for (int s = 128; s > 0; s >>= 1) {
        if (t < s) {
            #pragma unroll
            for (int i = 0; i < 6; ++i) red[i][t] += red[i][t + s];
        }
        __syncthreads();
    }
    if (t == 0) {
        float ccx = red[0][0] / (float)NN, ccy = red[1][0] / (float)NN, ccz = red[2][0] / (float)NN;
        float cnx = red[3][0] / (float)NN, cny = red[4][0] / (float)NN, cnz = red[5][0] / (float)NN;
        float inv = 1.0f / sqrtf(cnx * cnx + cny * cny + cnz * cnz);
        float* s9 = st + b * 16;
        s9[0] = ccx; s9[1] = ccy; s9[2] = ccz;
        s9[3] = cnx; s9[4] = cny; s9[5] = cnz;
        s9[6] = cnx * inv; s9[7] = cny * inv; s9[8] = cnz * inv;
    }
}

__device__ __forceinline__ float angle3(float ux, float uy, float uz,
                                        float vx, float vy, float vz) {
    float crx = uy * vz - uz * vy;
    float cry = uz * vx - ux * vz;
    float crz = ux * vy - uy * vx;
    float s = sqrtf(crx * crx + cry * cry + crz * crz);
    float c = ux * vx + uy * vy + uz * vz;
    return atan2f(s, c);
}

// ---------------------------------------------------------------------------
// per-point PPF (F0 rows 0..3) + packed projected vectors PQ = (x,y,z,|P|)
// ---------------------------------------------------------------------------
__global__ __launch_bounds__(256) void point_k(const float* __restrict__ in,
                                               const float* __restrict__ st,
                                               float4* __restrict__ PQ,
                                               float* __restrict__ F0) {
    int idx = blockIdx.x * 256 + threadIdx.x;
    int b = idx >> 11, n = idx & (NN - 1);
    const float* base = in + (size_t)b * 22 * NN;
    const float* s9 = st + b * 16;
    float cx = base[0 * NN + n], cy = base[1 * NN + n], cz = base[2 * NN + n];
    float nx = base[3 * NN + n], ny = base[4 * NN + n], nz = base[5 * NN + n];
    float inv = 1.0f / sqrtf(nx * nx + ny * ny + nz * nz);
    nx *= inv; ny *= inv; nz *= inv;
    float ccx = s9[0], ccy = s9[1], ccz = s9[2];
    float cnx = s9[3], cny = s9[4], cnz = s9[5];
    float ex = s9[6], ey = s9[7], ez = s9[8];
    float dx = cx - ccx, dy = cy - ccy, dz = cz - ccz;
    F0[0 * MM + idx] = angle3(cnx, cny, cnz, dx, dy, dz);
    F0[1 * MM + idx] = angle3(nx, ny, nz, dx, dy, dz);
    F0[2 * MM + idx] = angle3(cnx, cny, cnz, nx, ny, nz);
    F0[3 * MM + idx] = sqrtf(dx * dx + dy * dy + dz * dz);
    float dot = dx * ex + dy * ey + dz * ez;
    float px = dx - dot * cnx;
    float py = dy - dot * cny;
    float pz = dz - dot * cnz;
    PQ[idx] = make_float4(px, py, pz, sqrtf(px * px + py * py + pz * pz));
}

// ---------------------------------------------------------------------------
// per-row median of pairwise angles. ONE row per wave, u[32] FULLY register-
// resident (full unroll -> compile-time indices only). Monotone key =
// tan^2(th/2) = ss/(c+|a||b|)^2; key<=2.5e-11 -> +INF (reference's at<=1e-5
// -> 100, sorts last). Greedy 20-bit search for largest T with
// #{u < T} <= 1023 (one v_cmp per value per bit). Reconstruct once per row.
// ---------------------------------------------------------------------------
__global__ __launch_bounds__(256) void alpha_k(const float4* __restrict__ PQ,
                                               float* __restrict__ F0) {
    int row = blockIdx.x * 4 + (threadIdx.x >> 6);
    int lane = threadIdx.x & 63;
    int b = row >> 11;
    const float4* base = PQ + (size_t)b * NN;
    float4 a = base[row & (NN - 1)];
    unsigned u[32];
    #pragma unroll
    for (int s2 = 0; s2 < 32; ++s2) {
        float4 bv = base[s2 * 64 + lane];
        float cx = a.y * bv.z - a.z * bv.y;
        float cy = a.z * bv.x - a.x * bv.z;
        float cz = a.x * bv.y - a.y * bv.x;
        float ss = cx * cx + cy * cy + cz * cz;
        float dc = a.x * bv.x + a.y * bv.y + a.z * bv.z;
        float den = dc + a.w * bv.w;
        float rc = __builtin_amdgcn_rcpf(den);
        float key = ss * rc * rc;
        u[s2] = (key <= 2.5e-11f) ? 0x7F800000u : __float_as_uint(key);
    }
    unsigned T = 0u;
    for (int bit = 30; bit >= 11; --bit) {
        unsigned c = T | (1u << bit);
        int n = 0;
        #pragma unroll
        for (int s2 = 0; s2 < 32; ++s2)
            n += (int)__popcll(__ballot(u[s2] < c));
        if (n <= 1023) T = c;
    }
    if (lane == 0)
        F0[4 * MM + row] = 2.0f * atanf(sqrtf(__uint_as_float(T)));
}

// ---------------------------------------------------------------------------
// zero a small region (all SUMS slices + MAXB, contiguous)
// ---------------------------------------------------------------------------
__global__ void zero_k(float* __restrict__ p) {
    p[blockIdx.x * 256 + threadIdx.x] = 0.f;
}

// ---------------------------------------------------------------------------
// convert all weights to fp16 (K-pad for cls0, O-pad for cls3)
// ---------------------------------------------------------------------------
__global__ __launch_bounds__(256) void wconv_k(const float* __restrict__ w1, const float* __restrict__ w2,
                                               const float* __restrict__ w3, const float* __restrict__ w4,
                                               const float* __restrict__ w5, const float* __restrict__ w6,
                                               const float* __restrict__ w7, unsigned short* __restrict__ Wb) {
    int idx = blockIdx.x * 256 + threadIdx.x;
    unsigned short v;
    if (idx < 8192) v = f2h(w1[idx]);
    else if (idx < 24576) v = f2h(w2[idx - 8192]);
    else if (idx < 155648) v = f2h(w3[idx - 24576]);
    else if (idx < 770048) {
        int l = idx - 155648;
        int o = l / 2400, k = l - o * 2400;
        v = (k < 2384) ? f2h(w4[o * 2384 + k]) : (unsigned short)0;
    } else if (idx < 835584) v = f2h(w5[idx - 770048]);
    else if (idx < 868352) v = f2h(w6[idx - 835584]);
    else {
        int l = idx - 868352;
        int o = l >> 7, k = l & 127;
        v = (o < 50) ? f2h(w7[o * 128 + k]) : (unsigned short)0;
    }
    Wb[idx] = v;
}

// ---------------------------------------------------------------------------
// one-hot rows 0..15 of XCb + zero pad cols 2384..2399
// ---------------------------------------------------------------------------
__global__ __launch_bounds__(256) void onehot_k(const float* __restrict__ in,
                                                unsigned short* __restrict__ XCb) {
    int m = blockIdx.x * 256 + threadIdx.x;
    int b = m >> 11, n = m & (NN - 1);
    const float* src = in + (size_t)b * 22 * NN + 6 * NN + n;
    unsigned short vals[16];
    #pragma unroll
    for (int r = 0; r < 16; ++r) vals[r] = f2h(src[(size_t)r * NN]);
    ushort4* dst = (ushort4*)&XCb[(size_t)m * 2400];
    #pragma unroll
    for (int q = 0; q < 4; ++q)
        dst[q] = make_ushort4(vals[4 * q], vals[4 * q + 1], vals[4 * q + 2], vals[4 * q + 3]);
    ushort4 z = make_ushort4(0, 0, 0, 0);
    ushort4* pz = (ushort4*)&XCb[(size_t)m * 2400 + 2384];
    pz[0] = z; pz[1] = z; pz[2] = z; pz[3] = z;
}

// ---------------------------------------------------------------------------
// pf0: tiny K=5 GEMM, Y (M,64) fp32
// ---------------------------------------------------------------------------
__global__ __launch_bounds__(256) void pf0_k(const float* __restrict__ F0,
                                             const float* __restrict__ W,
                                             float* __restrict__ Y) {
    __shared__ float ws[320];
    int t = threadIdx.x;
    for (int i = t; i < 320; i += 256) ws[i] = W[i];
    __syncthreads();
    int m = blockIdx.x * 256 + t;
    float x0 = F0[m], x1 = F0[MM + m], x2 = F0[2 * MM + m], x3 = F0[3 * MM + m], x4 = F0[4 * MM + m];
    float* ym = Y + (size_t)m * 64;
    #pragma unroll
    for (int o = 0; o < 64; ++o) {
        const float* wo = &ws[o * 5];
        ym[o] = wo[0] * x0 + wo[1] * x1 + wo[2] * x2 + wo[3] * x3 + wo[4] * x4;
    }
}

// ---------------------------------------------------------------------------
// fp16 MFMA GEMM, pipelined: BM=64, BO=128, 4 waves, wave=32x64.
// MODE 0: fp32 Y write, no stats (supports K-split via blockIdx.z).
// MODE 1: fp16 Y write + fused BN-stat epilogue into sums slice.
// ---------------------------------------------------------------------------
template<int MODE>
__global__ __launch_bounds__(256) void mgemm3_k(const unsigned short* __restrict__ X, int ldx,
                                                const unsigned short* __restrict__ W, int ldw,
                                                void* __restrict__ Yv, int Co, int K, int kchunk,
                                                float* __restrict__ sums) {
    __shared__ unsigned short As[64 * 32];    // 4KB
    __shared__ unsigned short Bs[128 * 32];   // 8KB
    int t = threadIdx.x;
    int mBase = blockIdx.x * 64;
    int oBase = blockIdx.y * 128;
    int k0c = blockIdx.z * kchunk;
    int k1c = k0c + kchunk; if (k1c > K) k1c = K;
    int lane = t & 63, w = t >> 6;
    int warpM = (w & 1) * 32, warpO = (w >> 1) * 64;
    f32x4 acc[2][4];
    #pragma unroll
    for (int i = 0; i < 2; ++i)
        #pragma unroll
        for (int j = 0; j < 4; ++j) acc[i][j] = (f32x4){0.f, 0.f, 0.f, 0.f};
    int lr = t >> 2;
    int lc = (t & 3) * 8;
    const unsigned short* Xp = X + (size_t)(mBase + lr) * ldx + lc;
    const unsigned short* Wp0 = W + (size_t)(oBase + lr) * ldw + lc;
    const unsigned short* Wp1 = W + (size_t)(oBase + lr + 64) * ldw + lc;
    int ar0 = (warpM + (lane & 15)) * 32 + (lane >> 4) * 8;
    int br0 = (warpO + (lane & 15)) * 32 + (lane >> 4) * 8;
    uint4 xa = *(const uint4*)(Xp + k0c);
    uint4 wb0 = *(const uint4*)(Wp0 + k0c);
    uint4 wb1 = *(const uint4*)(Wp1 + k0c);
    for (int k = k0c; k < k1c; k += 32) {
        __syncthreads();
        *(uint4*)&As[lr * 32 + lc] = xa;
        *(uint4*)&Bs[lr * 32 + lc] = wb0;
        *(uint4*)&Bs[(lr + 64) * 32 + lc] = wb1;
        if (k + 32 < k1c) {
            xa = *(const uint4*)(Xp + k + 32);
            wb0 = *(const uint4*)(Wp0 + k + 32);
            wb1 = *(const uint4*)(Wp1 + k + 32);
        }
        __syncthreads();
        half8 a0 = __builtin_bit_cast(half8, *(const uint4*)&As[ar0]);
        half8 a1 = __builtin_bit_cast(half8, *(const uint4*)&As[ar0 + 16 * 32]);
        half8 b0 = __builtin_bit_cast(half8, *(const uint4*)&Bs[br0]);
        half8 b1 = __builtin_bit_cast(half8, *(const uint4*)&Bs[br0 + 16 * 32]);
        half8 b2 = __builtin_bit_cast(half8, *(const uint4*)&Bs[br0 + 32 * 32]);
        half8 b3 = __builtin_bit_cast(half8, *(const uint4*)&Bs[br0 + 48 * 32]);
        acc[0][0] = __builtin_amdgcn_mfma_f32_16x16x32_f16(a0, b0, acc[0][0], 0, 0, 0);
        acc[0][1] = __builtin_amdgcn_mfma_f32_16x16x32_f16(a0, b1, acc[0][1], 0, 0, 0);
        acc[0][2] = __builtin_amdgcn_mfma_f32_16x16x32_f16(a0, b2, acc[0][2], 0, 0, 0);
        acc[0][3] = __builtin_amdgcn_mfma_f32_16x16x32_f16(a0, b3, acc[0][3], 0, 0, 0);
        acc[1][0] = __builtin_amdgcn_mfma_f32_16x16x32_f16(a1, b0, acc[1][0], 0, 0, 0);
        acc[1][1] = __builtin_amdgcn_mfma_f32_16x16x32_f16(a1, b1, acc[1][1], 0, 0, 0);
        acc[1][2] = __builtin_amdgcn_mfma_f32_16x16x32_f16(a1, b2, acc[1][2], 0, 0, 0);
        acc[1][3] = __builtin_amdgcn_mfma_f32_16x16x32_f16(a1, b3, acc[1][3], 0, 0, 0);
    }
    if (MODE == 0) {
        float* Yp = (float*)Yv + (size_t)blockIdx.z * MM * Co;
        #pragma unroll
        for (int i = 0; i < 2; ++i)
            #pragma unroll
            for (int j = 0; j < 4; ++j) {
                int m0 = mBase + warpM + i * 16 + (lane >> 4) * 4;
                int o = oBase + warpO + j * 16 + (lane & 15);
                #pragma unroll
                for (int r = 0; r < 4; ++r)
                    Yp[(size_t)(m0 + r) * Co + o] = acc[i][j][r];
            }
    } else {
        unsigned short* Yh = (unsigned short*)Yv;
        #pragma unroll
        for (int i = 0; i < 2; ++i)
            #pragma unroll
            for (int j = 0; j < 4; ++j) {
                int m0 = mBase + warpM + i * 16 + (lane >> 4) * 4;
                int o = oBase + warpO + j * 16 + (lane & 15);
                #pragma unroll
                for (int r = 0; r < 4; ++r)
                    Yh[(size_t)(m0 + r) * Co + o] = f2h(acc[i][j][r]);
            }
        __syncthreads();
        float* ssum = (float*)As;
        float* ssq = (float*)Bs;
        if (t < 128) { ssum[t] = 0.f; ssq[t] = 0.f; }
        __syncthreads();
        #pragma unroll
        for (int j = 0; j < 4; ++j) {
            int oc = warpO + j * 16 + (lane & 15);
            float s = 0.f, q = 0.f;
            #pragma unroll
            for (int i = 0; i < 2; ++i)
                #pragma unroll
                for (int r = 0; r < 4; ++r) { float v = acc[i][j][r]; s += v; q += v * v; }
            atomicAdd(&ssum[oc], s);
            atomicAdd(&ssq[oc], q);
        }
        __syncthreads();
        if (t < 128) {
            atomicAdd(&sums[oBase + t], ssum[t]);
            atomicAdd(&sums[1024 + oBase + t], ssq[t]);
        }
    }
}

// ---------------------------------------------------------------------------
// fused: sum 4 cls0 K-split partials into partial 0 + BN stats, one pass.
// grid (4, 64): o-tile 64, m-tile 128 (rows m0 + 4i + mg).
// ---------------------------------------------------------------------------
__global__ __launch_bounds__(256) void red4stat_k(float* __restrict__ Y,
                                                  float* __restrict__ sums) {
    int o0 = blockIdx.x * 64;
    int m0 = blockIdx.y * 128;
    int t = threadIdx.x, ol = t & 63, mg = t >> 6;
    const size_t stride = (size_t)MM * 256;
    float s = 0.f, q = 0.f;
    float* p = Y + (size_t)(m0 + mg) * 256 + o0 + ol;
    for (int i = 0; i < 32; ++i) {
        float* pp = p + (size_t)i * 4 * 256;
        float v = pp[0] + pp[stride] + pp[2 * stride] + pp[3 * stride];
        pp[0] = v;
        s += v; q += v * v;
    }
    __shared__ float ls[4][64], lq[4][64];
    ls[mg][ol] = s; lq[mg][ol] = q;
    __syncthreads();
    if (mg == 0) {
        s = ls[0][ol] + ls[1][ol] + ls[2][ol] + ls[3][ol];
        q = lq[0][ol] + lq[1][ol] + lq[2][ol] + lq[3][ol];
        atomicAdd(&sums[o0 + ol], s);
        atomicAdd(&sums[1024 + o0 + ol], q);
    }
}

// ---------------------------------------------------------------------------
// BN stats from fp32 Y (pf0) into a sums slice
// ---------------------------------------------------------------------------
__global__ __launch_bounds__(256) void bnstat_k(const float* __restrict__ Y, int Co,
                                                float* __restrict__ sums) {
    int o0 = blockIdx.x * 64;
    int m0 = blockIdx.y * 512;
    int t = threadIdx.x, ol = t & 63, mg = t >> 6;
    float s = 0.f, q = 0.f;
    const float* p = Y + (size_t)(m0 + mg) * Co + o0 + ol;
    for (int i = 0; i < 128; ++i) {
        float v = p[(size_t)i * 4 * Co];
        s += v; q += v * v;
    }
    __shared__ float ls[4][64], lq[4][64];
    ls[mg][ol] = s; lq[mg][ol] = q;
    __syncthreads();
    if (mg == 0) {
        s = ls[0][ol] + ls[1][ol] + ls[2][ol] + ls[3][ol];
        q = lq[0][ol] + lq[1][ol] + lq[2][ol] + lq[3][ol];
        atomicAdd(&sums[o0 + ol], s);
        atomicAdd(&sums[1024 + o0 + ol], q);
    }
}

// inline BN coefficient from sums slice
__device__ __forceinline__ void bncoef(const float* __restrict__ sums,
                                       const float* __restrict__ g,
                                       const float* __restrict__ bb,
                                       int o, float& a, float& c) {
    float mu = sums[o] * (1.f / 8192.f);
    float var = sums[1024 + o] * (1.f / 8192.f) - mu * mu;
    var = fmaxf(var, 0.f);
    a = g[o] * (1.0f / sqrtf(var + EPSF));
    c = bb[o] - mu * a;
}

// ---------------------------------------------------------------------------
// BN normalize + ReLU + fp16 store (fp32 source)
// ---------------------------------------------------------------------------
__global__ __launch_bounds__(256) void bnorm_f(const float* __restrict__ Y,
                                               const float* __restrict__ sums,
                                               const float* __restrict__ g,
                                               const float* __restrict__ bb,
                                               unsigned short* __restrict__ dst, int ldd, int shift) {
    int idx4 = blockIdx.x * 256 + threadIdx.x;
    int m = idx4 >> shift;
    int o4 = (idx4 & ((1 << shift) - 1)) * 4;
    float4 v = ((const float4*)Y)[idx4];
    float vv[4] = {v.x, v.y, v.z, v.w};
    unsigned short r[4];
    #pragma unroll
    for (int j = 0; j < 4; ++j) {
        float a, c;
        bncoef(sums, g, bb, o4 + j, a, c);
        r[j] = f2h(fmaxf(vv[j] * a + c, 0.f));
    }
    *(ushort4*)&dst[(size_t)m * ldd + o4] = make_ushort4(r[0], r[1], r[2], r[3]);
}

// ---------------------------------------------------------------------------
// BN normalize + ReLU + fp16 store (fp16 source)
// ---------------------------------------------------------------------------
__global__ __launch_bounds__(256) void bnorm_h(const unsigned short* __restrict__ Yh,
                                               const float* __restrict__ sums,
                                               const float* __restrict__ g,
                                               const float* __restrict__ bb,
                                               unsigned short* __restrict__ dst, int ldd, int shift) {
    int idx4 = blockIdx.x * 256 + threadIdx.x;
    int m = idx4 >> shift;
    int o4 = (idx4 & ((1 << shift) - 1)) * 4;
    ushort4 hv = ((const ushort4*)Yh)[idx4];
    float vv[4] = {h2f(hv.x), h2f(hv.y), h2f(hv.z), h2f(hv.w)};
    unsigned short r[4];
    #pragma unroll
    for (int j = 0; j < 4; ++j) {
        float a, c;
        bncoef(sums, g, bb, o4 + j, a, c);
        r[j] = f2h(fmaxf(vv[j] * a + c, 0.f));
    }
    *(ushort4*)&dst[(size_t)m * ldd + o4] = make_ushort4(r[0], r[1], r[2], r[3]);
}

// ---------------------------------------------------------------------------
// max over N per (b, channel) from pf3's fp16 slice
// ---------------------------------------------------------------------------
__global__ __launch_bounds__(256) void maxred_k(const unsigned short* __restrict__ Xs,
                                                float* __restrict__ maxbuf) {
    int o0 = blockIdx.x * 64;
    int b = blockIdx.y;
    int rc = blockIdx.z;
    int t = threadIdx.x, ol = t & 63, mg = t >> 6;
    float mx = 0.f;
    for (int i = 0; i < 128; ++i) {
        int m = b * NN + rc * 512 + i * 4 + mg;
        mx = fmaxf(mx, h2f(Xs[(size_t)m * 2400 + o0 + ol]));
    }
    __shared__ float ls[4][64];
    ls[mg][ol] = mx;
    __syncthreads();
    if (mg == 0) {
        mx = fmaxf(fmaxf(ls[0][ol], ls[1][ol]), fmaxf(ls[2][ol], ls[3][ol]));
        atomicMax((unsigned*)&maxbuf[b * 1024 + o0 + ol], __builtin_bit_cast(unsigned, mx));
    }
}

__global__ __launch_bounds__(256) void maxbc_k(const float* __restrict__ maxbuf,
                                               unsigned short* __restrict__ XCb) {
    int idx8 = blockIdx.x * 256 + threadIdx.x;
    int m = idx8 >> 7;
    int o8 = (idx8 & 127) * 8;
    int b = m >> 11;
    const float* mb = maxbuf + b * 1024 + o8;
    ushort4 u0 = make_ushort4(f2h(mb[0]), f2h(mb[1]), f2h(mb[2]), f2h(mb[3]));
    ushort4 u1 = make_ushort4(f2h(mb[4]), f2h(mb[5]), f2h(mb[6]), f2h(mb[7]));
    *(ushort4*)&XCb[(size_t)m * 2400 + 1360 + o8] = u0;
    *(ushort4*)&XCb[(size_t)m * 2400 + 1360 + o8 + 4] = u1;
}

// ---------------------------------------------------------------------------
// final: OT(M,128) fp32 -> out (B,50,N) + bias, via LDS transpose
// ---------------------------------------------------------------------------
__global__ __launch_bounds__(256) void wout_k(const float* __restrict__ OT,
                                              const float* __restrict__ bias,
                                              float* __restrict__ out) {
    __shared__ float ts[128][65];
    int t = threadIdx.x;
    int m0 = blockIdx.x * 128;
    #pragma unroll
    for (int i = 0; i < 8; ++i) {
        int idx4 = t + 256 * i;
        int row = idx4 >> 4, c4 = (idx4 & 15) * 4;
        float4 v = *(const float4*)&OT[(size_t)(m0 + row) * 128 + c4];
        ts[row][c4] = v.x; ts[row][c4 + 1] = v.y; ts[row][c4 + 2] = v.z; ts[row][c4 + 3] = v.w;
    }
    __syncthreads();
    int b = m0 >> 11, n0 = m0 & (NN - 1);
    #pragma unroll
    for (int j = 0; j < 25; ++j) {
        int idx = t + 256 * j;
        int o = idx >> 7, nl = idx & 127;
        out[((size_t)b * 50 + o) * NN + n0 + nl] = ts[nl][o] + bias[o];
    }
}

// ---------------------------------------------------------------------------
extern "C" void kernel_launch(void* const* d_in, const int* in_sizes, int n_in,
                              void* d_out, int out_size, void* d_ws, size_t ws_size,
                              hipStream_t stream) {
    const float* in = (const float*)d_in[0];
    const float* pf0_w = (const float*)d_in[1];
    const float* pf_g[4] = {(const float*)d_in[2], (const float*)d_in[5], (const float*)d_in[8], (const float*)d_in[11]};
    const float* pf_b[4] = {(const float*)d_in[3], (const float*)d_in[6], (const float*)d_in[9], (const float*)d_in[12]};
    const float* pf_w[4] = {(const float*)d_in[1], (const float*)d_in[4], (const float*)d_in[7], (const float*)d_in[10]};
    const float* cls_w[3] = {(const float*)d_in[13], (const float*)d_in[16], (const float*)d_in[19]};
    const float* cls_g[3] = {(const float*)d_in[14], (const float*)d_in[17], (const float*)d_in[20]};
    const float* cls_b[3] = {(const float*)d_in[15], (const float*)d_in[18], (const float*)d_in[21]};
    const float* cls3_w = (const float*)d_in[22];
    const float* cls3_bias = (const float*)d_in[23];
    float* out = (float*)d_out;

    char* wsb = (char*)d_ws;
    float* ST = (float*)(wsb + 0);                      // 256 B
    float4* PQ = (float4*)(wsb + 256);                  // 131072 B
    float* F0 = (float*)(wsb + 131328);                 // 163840 B
    float* SUMS = (float*)(wsb + 295168);               // 7 slices x 8192 B = 57344 B
    float* MAXB = (float*)(wsb + 352512);               // 16384 B (right after SUMS)
    unsigned short* WB = (unsigned short*)(wsb + 368896);    // 1769472 B
    unsigned short* XCb = (unsigned short*)(wsb + 2138368);  // 39321600 B
    unsigned short* C1b = (unsigned short*)(wsb + 41459968); // 4194304 B (aliased as C3b)
    unsigned short* C2b = (unsigned short*)(wsb + 45654272); // 4194304 B
    unsigned short* C3b = C1b;
    float* Y = (float*)(wsb + 49848576);                // 33554432 B (4 cls0 partials)
    unsigned short* Yh = (unsigned short*)Y;

    auto SL = [&](int s) { return SUMS + (size_t)s * 2048; };

    zero_k<<<72, 256, 0, stream>>>(SUMS);  // 7 SUMS slices + MAXB (contiguous)
    wconv_k<<<3456, 256, 0, stream>>>(pf_w[1], pf_w[2], pf_w[3], cls_w[0], cls_w[1], cls_w[2], cls3_w, WB);
    stats_k<<<BB, 256, 0, stream>>>(in, ST);
    point_k<<<MM / 256, 256, 0, stream>>>(in, ST, PQ, F0);
    alpha_k<<<MM / 4, 256, 0, stream>>>(PQ, F0);
    onehot_k<<<MM / 256, 256, 0, stream>>>(in, XCb);

    // pf0 (fp32 path)
    pf0_k<<<MM / 256, 256, 0, stream>>>(F0, pf0_w, Y);
    bnstat_k<<<dim3(1, 16), 256, 0, stream>>>(Y, 64, SL(0));
    bnorm_f<<<512, 256, 0, stream>>>(Y, SL(0), pf_g[0], pf_b[0], XCb + 16, 2400, 4);
    // pf1 (Co=128, K=64)
    mgemm3_k<1><<<dim3(128, 1, 1), 256, 0, stream>>>(XCb + 16, 2400, WB, 64, Yh, 128, 64, 64, SL(1));
    bnorm_h<<<1024, 256, 0, stream>>>(Yh, SL(1), pf_g[1], pf_b[1], XCb + 80, 2400, 5);
    // pf2 (Co=128, K=128)
    mgemm3_k<1><<<dim3(128, 1, 1), 256, 0, stream>>>(XCb + 80, 2400, WB + 8192, 128, Yh, 128, 128, 128, SL(2));
    bnorm_h<<<1024, 256, 0, stream>>>(Yh, SL(2), pf_g[2], pf_b[2], XCb + 208, 2400, 5);
    // pf3 (Co=1024, K=128)
    mgemm3_k<1><<<dim3(128, 8, 1), 256, 0, stream>>>(XCb + 208, 2400, WB + 24576, 128, Yh, 1024, 128, 128, SL(3));
    bnorm_h<<<8192, 256, 0, stream>>>(Yh, SL(3), pf_g[3], pf_b[3], XCb + 336, 2400, 8);
    // max feature
    maxred_k<<<dim3(16, 4, 4), 256, 0, stream>>>(XCb + 336, MAXB);
    maxbc_k<<<4096, 256, 0, stream>>>(MAXB, XCb);
    // cls0 (Co=256, K=2400): K-split x4, fp32 partials, fused reduce+stats, norm
    mgemm3_k<0><<<dim3(128, 2, 4), 256, 0, stream>>>(XCb, 2400, WB + 155648, 2400, Y, 256, 2400, 608, SL(4));
    red4stat_k<<<dim3(4, 64), 256, 0, stream>>>(Y, SL(4));
    bnorm_f<<<2048, 256, 0, stream>>>(Y, SL(4), cls_g[0], cls_b[0], C1b, 256, 6);
    // cls1 (Co=256, K=256)
    mgemm3_k<1><<<dim3(128, 2, 1), 256, 0, stream>>>(C1b, 256, WB + 770048, 256, Yh, 256, 256, 256, SL(5));
    bnorm_h<<<2048, 256, 0, stream>>>(Yh, SL(5), cls_g[1], cls_b[1], C2b, 256, 6);
    // cls2 (Co=128, K=256)
    mgemm3_k<1><<<dim3(128, 1, 1), 256, 0, stream>>>(C2b, 256, WB + 835584, 256, Yh, 128, 256, 256, SL(6));
    bnorm_h<<<1024, 256, 0, stream>>>(Yh, SL(6), cls_g[2], cls_b[2], C3b, 128, 5);
    // cls3 (padded to 128 outputs, rows 50..127 zero) -> fp32 Y
    mgemm3_k<0><<<dim3(128, 1, 1), 256, 0, stream>>>(C3b, 128, WB + 868352, 128, Y, 128, 128, 128, SL(0));
    wout_k<<<MM / 128, 256, 0, stream>>>(Y, cls3_bias, out);

    (void)in_sizes; (void)n_in; (void)out_size; (void)ws_size;
}